// Round 11
// baseline (563.677 us; speedup 1.0000x reference)
//
#include <hip/hip_runtime.h>
#include <hip/hip_bf16.h>
#include <hip/hip_cooperative_groups.h>

namespace cg = cooperative_groups;

typedef __hip_bfloat16 bf16;
typedef __attribute__((ext_vector_type(8))) short short8;   // 8 bf16 = 4 VGPRs
typedef __attribute__((ext_vector_type(4))) float float4v;  // MFMA C/D
typedef __attribute__((ext_vector_type(4))) short short4v;

__device__ __forceinline__ short f2bs(float x) {
    bf16 b = __float2bfloat16(x);
    return *reinterpret_cast<short*>(&b);
}
__device__ __forceinline__ float bs2f(short s) {
    bf16 b = *reinterpret_cast<bf16*>(&s);
    return __bfloat162float(b);
}

#define GLL16(g, l) __builtin_amdgcn_global_load_lds(                      \
    (const __attribute__((address_space(1))) void*)(g),                    \
    (__attribute__((address_space(3))) void*)(l), 16, 0, 0)

// ---------------- preprocessing: f32 -> padded bf16 layouts ----------------

// emb (50000,300) f32 -> emb_bf (50176,320) bf16. float4 loads.
__global__ __launch_bounds__(256) void conv_emb(
    const float* __restrict__ src, short* __restrict__ dst)
{
    const int idx = blockIdx.x * 256 + threadIdx.x;      // 50176*80
    if (idx >= 50176 * 80) return;
    const int row = idx / 80;
    const int k4  = (idx - row * 80) * 4;
    short4v v = (short4v)0;
    if (row < 50000 && k4 < 300) {
        const float4v f = *reinterpret_cast<const float4v*>(
            src + (long)row * 300 + k4);
#pragma unroll
        for (int j = 0; j < 4; ++j) v[j] = f2bs(f[j]);
    }
    *(short4v*)&dst[(long)row * 320 + k4] = v;
}

// Fused weight prep: W_h -> Bh (320x640), W_leaf -> Bleaf (320x320),
// b_h -> biasp (320).
__global__ __launch_bounds__(256) void conv_w(
    const float* __restrict__ W_h, const float* __restrict__ W_leaf,
    const float* __restrict__ b_h, short* __restrict__ Bh,
    short* __restrict__ Bleaf, float* __restrict__ biasp)
{
    const int idx = blockIdx.x * 256 + threadIdx.x;
    if (idx < 204800) {                                   // Bh 320x640
        const int row = idx / 640, k = idx - row * 640;
        float v = 0.f;
        if (row < 300) {
            if (k < 300)                  v = W_h[row * 600 + k];
            else if (k >= 320 && k < 620) v = W_h[row * 600 + k - 20];
        }
        Bh[idx] = f2bs(v);
    } else if (idx < 307200) {                            // Bleaf 320x320
        const int i = idx - 204800;
        const int row = i / 320, k = i - row * 320;
        Bleaf[i] = (row < 300 && k < 300) ? f2bs(W_leaf[row * 300 + k])
                                          : (short)0;
    } else if (idx < 307520) {                            // biasp 320
        const int i = idx - 307200;
        biasp[i] = (i < 300) ? b_h[i] : 0.f;
    }
}

// ---------------- MFMA GEMM (BK=32, 2-buf, 1-deep counted vmcnt) ----------
// Used for Hv (throughput, KE=320) and L1 (gather, KE=640, 2 blocks/CU TLP).
template <int KE, int GMODE, bool BIAS>
__global__ __launch_bounds__(256, 2) void mfma_gemm(
    const short* __restrict__ Xsrc, const int* __restrict__ wid,
    const short* __restrict__ emb, const short* __restrict__ Wp,
    const float* __restrict__ biasp, short* __restrict__ out)
{
    static_assert(GMODE != 2 || KE == 640, "pair-gather requires KE=640");
    __shared__ __align__(16) short As[2][128 * 32];   // 2 x 8 KB
    __shared__ __align__(16) short Bs[2][320 * 32];   // 2 x 20 KB

    const int tid  = threadIdx.x;
    const int lane = tid & 63;
    const int w    = tid >> 6;
    const int wm   = w >> 1, wn = w & 1;
    const long m0  = (long)blockIdx.x * 128;

    const int s_q   = lane & 3;
    const int r_off = lane >> 2;

    const char* gL[2];
    const char* gR[2];
#pragma unroll
    for (int j = 0; j < 2; ++j) {
        const int r = (w * 2 + j) * 16 + r_off;            // 0..127
        const int q = s_q ^ ((r >> 1) & 3);
        if (GMODE == 2) {
            const long node = m0 + r;
            gL[j] = (const char*)emb + (long)wid[2 * node]     * 640 + q * 16;
            gR[j] = (const char*)emb + (long)wid[2 * node + 1] * 640 + q * 16;
        } else {
            gL[j] = (const char*)Xsrc + (m0 + r) * (long)(KE * 2) + q * 16;
            gR[j] = gL[j];
        }
    }
    const char* gB[5];
#pragma unroll
    for (int j = 0; j < 5; ++j) {
        const int r = (w * 5 + j) * 16 + r_off;            // 0..319
        const int q = s_q ^ ((r >> 1) & 3);
        gB[j] = (const char*)Wp + r * (long)(KE * 2) + q * 16;
    }

    int oA[4];
#pragma unroll
    for (int t = 0; t < 4; ++t) {
        const int row = wm * 64 + t * 16 + (lane & 15);
        const int s   = (lane >> 4) ^ ((row >> 1) & 3);
        oA[t] = row * 32 + s * 8;
    }
    int oB[10];
#pragma unroll
    for (int u = 0; u < 10; ++u) {
        const int n = wn * 160 + u * 16 + (lane & 15);
        const int s = (lane >> 4) ^ ((n >> 1) & 3);
        oB[u] = n * 32 + s * 8;
    }

    auto stage = [&](int buf, int kc) {
        char* baseA = (char*)&As[buf][0];
        char* baseB = (char*)&Bs[buf][0];
        if (GMODE == 2) {
            const bool lft = (kc < 10);
            const int off = (lft ? kc : kc - 10) * 64;
            GLL16((lft ? gL[0] : gR[0]) + off, baseA + (w * 2 + 0) * 1024);
            GLL16((lft ? gL[1] : gR[1]) + off, baseA + (w * 2 + 1) * 1024);
        } else {
            const int off = kc * 64;
            GLL16(gL[0] + off, baseA + (w * 2 + 0) * 1024);
            GLL16(gL[1] + off, baseA + (w * 2 + 1) * 1024);
        }
        const int offb = kc * 64;
#pragma unroll
        for (int j = 0; j < 5; ++j)
            GLL16(gB[j] + offb, baseB + (w * 5 + j) * 1024);
    };

    float4v acc[4][10];
#pragma unroll
    for (int t = 0; t < 4; ++t)
#pragma unroll
        for (int u = 0; u < 10; ++u) acc[t][u] = (float4v)0.f;

    const int NCH = KE / 32;
    stage(0, 0);
    for (int kc = 0; kc < NCH; ++kc) {
        const int cur = kc & 1;
        if (kc + 1 < NCH) {
            stage(cur ^ 1, kc + 1);
            asm volatile("s_waitcnt vmcnt(7)" ::: "memory");
        } else {
            asm volatile("s_waitcnt vmcnt(0)" ::: "memory");
        }
        __builtin_amdgcn_s_barrier();
        __builtin_amdgcn_sched_barrier(0);

        const short* bA = &As[cur][0];
        const short* bB = &Bs[cur][0];
        short8 a[4], b[10];
#pragma unroll
        for (int t = 0; t < 4; ++t) a[t] = *(const short8*)(bA + oA[t]);
#pragma unroll
        for (int u = 0; u < 10; ++u) b[u] = *(const short8*)(bB + oB[u]);
#pragma unroll
        for (int u = 0; u < 10; ++u)
#pragma unroll
            for (int t = 0; t < 4; ++t)
                acc[t][u] = __builtin_amdgcn_mfma_f32_16x16x32_bf16(
                    a[t], b[u], acc[t][u], 0, 0, 0);
        __builtin_amdgcn_s_barrier();
    }

#pragma unroll
    for (int u = 0; u < 10; ++u) {
        const int c = wn * 160 + u * 16 + (lane & 15);
        const float bv = BIAS ? biasp[c] : 0.f;
#pragma unroll
        for (int t = 0; t < 4; ++t) {
            const long mb = m0 + wm * 64 + t * 16 + (lane >> 4) * 4;
#pragma unroll
            for (int r4 = 0; r4 < 4; ++r4)
                out[(mb + r4) * 320 + c] = f2bs(acc[t][u][r4] + bv);
        }
    }
}

// ---------------- cooperative tree tail: L2..L8 + classifier --------------
// One launch replaces 7 level kernels + cls (evidence: removing launches is
// the only action that moved the total; ~7-10 us/launch). 256 blocks x 512
// thr, 112 KB LDS -> exactly 1 block/CU (co-residency for grid.sync()).
// Per-level tile body == round-10 mfma_bk (bit-identical math): BK=128 in
// 4 x 32-k planes, plane order preserves BK=32 accumulation order.
__global__ __launch_bounds__(512, 1) void tree_tail(
    short* bufA, short* bufB, const short* __restrict__ Wp,
    const float* __restrict__ biasp, const float* __restrict__ W_cls,
    const float* __restrict__ b_cls, float* __restrict__ outp)
{
    __shared__ __align__(16) short As[4 * 128 * 32];   // 32 KB
    __shared__ __align__(16) short Bs[4 * 320 * 32];   // 80 KB

    cg::grid_group grid = cg::this_grid();

    const int tid  = threadIdx.x;
    const int lane = tid & 63;
    const int w    = tid >> 6;            // 0..7
    const int wm   = w >> 2;              // 0..1 -> M-tile 64
    const int wn   = w & 3;               // 0..3 -> N-tile 80
    const int s_q   = lane & 3;
    const int r_off = lane >> 2;          // 0..15

    // B staging slots (level-invariant; Wp fixed all levels)
    const char* gB[10];
    int pB[10], loB[10];
#pragma unroll
    for (int i = 0; i < 10; ++i) {
        const int gid = w * 10 + i;
        const int p   = gid / 20;                       // plane 0..3
        const int grp = gid - p * 20;                   // 16-row group
        const int r   = grp * 16 + r_off;               // 0..319
        const int q   = s_q ^ ((r >> 1) & 3);
        gB[i]  = (const char*)Wp + r * 1280L + q * 16;
        pB[i]  = p;
        loB[i] = p * 20480 + grp * 1024;                // bytes into Bs
    }

    // A staging row (per-tile base recomputed), fragment offsets
    const int rA = w * 16 + r_off;                      // 0..127
    const int qA = s_q ^ ((rA >> 1) & 3);
    int oA[4];
#pragma unroll
    for (int t = 0; t < 4; ++t) {
        const int row = wm * 64 + t * 16 + (lane & 15);
        const int s   = (lane >> 4) ^ ((row >> 1) & 3);
        oA[t] = row * 32 + s * 8;
    }
    int oB[5];
#pragma unroll
    for (int u = 0; u < 5; ++u) {
        const int n = wn * 80 + u * 16 + (lane & 15);
        const int s = (lane >> 4) ^ ((n >> 1) & 3);
        oB[u] = n * 32 + s * 8;
    }

    short* cur = bufA;
    short* nxt = bufB;
    int nodes = 65536;
    for (int l = 0; l < 7; ++l) {
        const int nt = nodes >> 7;                      // tiles of 128 rows
        for (int t0 = blockIdx.x; t0 < nt; t0 += 256) {
            const long m0 = (long)t0 * 128;
            const char* gA = (const char*)cur + (m0 + rA) * 1280L + qA * 16;

            float4v acc[4][5];
#pragma unroll
            for (int t = 0; t < 4; ++t)
#pragma unroll
                for (int u = 0; u < 5; ++u) acc[t][u] = (float4v)0.f;

            for (int kc = 0; kc < 5; ++kc) {
#pragma unroll
                for (int p = 0; p < 4; ++p)
                    GLL16(gA + (long)(kc * 4 + p) * 64,
                          (char*)As + p * 8192 + w * 1024);
#pragma unroll
                for (int i = 0; i < 10; ++i)
                    GLL16(gB[i] + (long)(kc * 4 + pB[i]) * 64,
                          (char*)Bs + loB[i]);

                asm volatile("s_waitcnt vmcnt(0)" ::: "memory");
                __builtin_amdgcn_s_barrier();
                __builtin_amdgcn_sched_barrier(0);

#pragma unroll
                for (int p = 0; p < 4; ++p) {
                    const short* bA = As + p * 4096;
                    const short* bB = Bs + p * 10240;
                    short8 a[4], b[5];
#pragma unroll
                    for (int t = 0; t < 4; ++t)
                        a[t] = *(const short8*)(bA + oA[t]);
#pragma unroll
                    for (int u = 0; u < 5; ++u)
                        b[u] = *(const short8*)(bB + oB[u]);
#pragma unroll
                    for (int u = 0; u < 5; ++u)
#pragma unroll
                        for (int t = 0; t < 4; ++t)
                            acc[t][u] =
                                __builtin_amdgcn_mfma_f32_16x16x32_bf16(
                                    a[t], b[u], acc[t][u], 0, 0, 0);
                }
                __builtin_amdgcn_s_barrier();
            }

#pragma unroll
            for (int u = 0; u < 5; ++u) {
                const int c = wn * 80 + u * 16 + (lane & 15);
                const float bv = biasp[c];
#pragma unroll
                for (int t = 0; t < 4; ++t) {
                    const long mb = m0 + wm * 64 + t * 16 + (lane >> 4) * 4;
#pragma unroll
                    for (int r4 = 0; r4 < 4; ++r4)
                        nxt[(mb + r4) * 320 + c] = f2bs(acc[t][u][r4] + bv);
                }
            }
        }
        grid.sync();                       // level complete, device-visible
        short* tswap = cur; cur = nxt; nxt = tswap;
        nodes >>= 1;
    }
    // roots now in cur (== bufB after 7 swaps): 1024 rows x 320 = 512 x 640.
    // Classifier: waves 0,1 of each block handle root rows 2*bid, 2*bid+1.
    if (w < 2) {
        const int b = blockIdx.x * 2 + w;               // 0..511
        const short* row = cur + (long)b * 640;
        float a0 = 0.f, a1 = 0.f, a2 = 0.f;
#pragma unroll
        for (int i = 0; i < 10; ++i) {
            const int k = lane + 64 * i;
            if (k < 600) {
                const int col = (k < 300) ? k : k + 20;
                const float f = 1.f / (1.f + __expf(-bs2f(row[col])));
                a0 += f * W_cls[k];
                a1 += f * W_cls[600 + k];
                a2 += f * W_cls[1200 + k];
            }
        }
#pragma unroll
        for (int off = 32; off > 0; off >>= 1) {
            a0 += __shfl_down(a0, off);
            a1 += __shfl_down(a1, off);
            a2 += __shfl_down(a2, off);
        }
        if (lane == 0) {
            const float l0 = a0 + b_cls[0];
            const float l1 = a1 + b_cls[1];
            const float l2 = a2 + b_cls[2];
            const float m  = fmaxf(l0, fmaxf(l1, l2));
            const float s  = __expf(l0 - m) + __expf(l1 - m) + __expf(l2 - m);
            const float ls = m + __logf(s);
            outp[b * 3 + 0] = l0 - ls;
            outp[b * 3 + 1] = l1 - ls;
            outp[b * 3 + 2] = l2 - ls;
        }
    }
}

extern "C" void kernel_launch(void* const* d_in, const int* in_sizes, int n_in,
                              void* d_out, int out_size, void* d_ws, size_t ws_size,
                              hipStream_t stream)
{
    const int*   wid    = (const int*)d_in[0];     // (512,2,256) int32
    const float* emb    = (const float*)d_in[1];   // (50000,300) f32
    const float* W_leaf = (const float*)d_in[2];   // (300,300)
    const float* W_h    = (const float*)d_in[3];   // (300,600)
    const float* b_h    = (const float*)d_in[4];   // (300,)
    const float* W_cls  = (const float*)d_in[5];   // (3,600)
    const float* b_cls  = (const float*)d_in[6];   // (3,)
    float* outp = (float*)d_out;                   // (512,3) f32

    (void)in_sizes; (void)n_in; (void)out_size; (void)ws_size;

    // ws layout (peak 158,557,440 B):
    //   bufA   @ 0           : 131072*320*2 =  83,886,080  (tree ping)
    //   bufB   @  83,886,080 :  65536*320*2 =  41,943,040  (tree pong)
    //   emb_bf @  83,886,080 : 50176*320*2  =  32,112,640  (ALIASES bufB: dead
    //            after Hv GEMM; bufB first written inside tree_tail L2)
    //   Hv     @ 125,829,120 : 50176*320*2  =  32,112,640
    //   Bleaf  @ 157,941,760 : 320*320*2    =     204,800
    //   Bh     @ 158,146,560 : 320*640*2    =     409,600
    //   biasp  @ 158,556,160 : 320*4        =       1,280
    char* ws = (char*)d_ws;
    short* bufA   = (short*)(ws);
    short* bufB   = (short*)(ws + 83886080);
    short* emb_bf = (short*)(ws + 83886080);
    short* Hv     = (short*)(ws + 125829120);
    short* Bleaf  = (short*)(ws + 157941760);
    short* Bh     = (short*)(ws + 158146560);
    float* biasp  = (float*)(ws + 158556160);

    conv_emb<<<(50176 * 80) / 256, 256, 0, stream>>>(emb, emb_bf);
    conv_w  <<<(307520 + 255) / 256, 256, 0, stream>>>(
        W_h, W_leaf, b_h, Bh, Bleaf, biasp);

    // Vocab-level leaf transform: Hv = emb_bf @ Bleaf^T, M=50176.
    mfma_gemm<320, 0, false><<<50176 / 128, 256, 0, stream>>>(
        emb_bf, nullptr, nullptr, Bleaf, biasp, Hv);

    // L1: node m = W_h @ concat(Hv[wid[2m]], Hv[wid[2m+1]]) + b_h -> bufA.
    mfma_gemm<640, 2, true><<<131072 / 128, 256, 0, stream>>>(
        nullptr, wid, Hv, Bh, biasp, bufA);

    // L2..L8 + classifier: single cooperative launch (grid.sync per level).
    {
        short* tA = bufA; short* tB = bufB;
        const short* tW = Bh; const float* tb = biasp;
        const float* tc = W_cls; const float* td = b_cls;
        float* to = outp;
        void* ka[] = {&tA, &tB, &tW, &tb, &tc, &td, &to};
        hipLaunchCooperativeKernel((void*)tree_tail, dim3(256), dim3(512),
                                   ka, 0, stream);
    }
}

// Round 14
// 343.791 us; speedup vs baseline: 1.6396x; 1.6396x over previous
//
#include <hip/hip_runtime.h>
#include <hip/hip_bf16.h>

typedef __hip_bfloat16 bf16;
typedef __attribute__((ext_vector_type(8))) short short8;   // 8 bf16 = 4 VGPRs
typedef __attribute__((ext_vector_type(4))) float float4v;  // MFMA C/D
typedef __attribute__((ext_vector_type(4))) short short4v;

__device__ __forceinline__ short f2bs(float x) {
    bf16 b = __float2bfloat16(x);
    return *reinterpret_cast<short*>(&b);
}
__device__ __forceinline__ float bs2f(short s) {
    bf16 b = *reinterpret_cast<bf16*>(&s);
    return __bfloat162float(b);
}

#define GLL16(g, l) __builtin_amdgcn_global_load_lds(                      \
    (const __attribute__((address_space(1))) void*)(g),                    \
    (__attribute__((address_space(3))) void*)(l), 16, 0, 0)

// ---------------- preprocessing: f32 -> padded bf16 layouts ----------------

// emb (50000,300) f32 -> emb_bf (50176,320) bf16. float4 loads.
__global__ __launch_bounds__(256) void conv_emb(
    const float* __restrict__ src, short* __restrict__ dst)
{
    const int idx = blockIdx.x * 256 + threadIdx.x;      // 50176*80
    if (idx >= 50176 * 80) return;
    const int row = idx / 80;
    const int k4  = (idx - row * 80) * 4;
    short4v v = (short4v)0;
    if (row < 50000 && k4 < 300) {
        const float4v f = *reinterpret_cast<const float4v*>(
            src + (long)row * 300 + k4);
#pragma unroll
        for (int j = 0; j < 4; ++j) v[j] = f2bs(f[j]);
    }
    *(short4v*)&dst[(long)row * 320 + k4] = v;
}

// Fused weight prep: W_h -> Bh (320x640), W_leaf -> Bleaf (320x320),
// b_h -> biasp (320).
__global__ __launch_bounds__(256) void conv_w(
    const float* __restrict__ W_h, const float* __restrict__ W_leaf,
    const float* __restrict__ b_h, short* __restrict__ Bh,
    short* __restrict__ Bleaf, float* __restrict__ biasp)
{
    const int idx = blockIdx.x * 256 + threadIdx.x;
    if (idx < 204800) {                                   // Bh 320x640
        const int row = idx / 640, k = idx - row * 640;
        float v = 0.f;
        if (row < 300) {
            if (k < 300)                  v = W_h[row * 600 + k];
            else if (k >= 320 && k < 620) v = W_h[row * 600 + k - 20];
        }
        Bh[idx] = f2bs(v);
    } else if (idx < 307200) {                            // Bleaf 320x320
        const int i = idx - 204800;
        const int row = i / 320, k = i - row * 320;
        Bleaf[i] = (row < 300 && k < 300) ? f2bs(W_leaf[row * 300 + k])
                                          : (short)0;
    } else if (idx < 307520) {                            // biasp 320
        const int i = idx - 307200;
        biasp[i] = (i < 300) ? b_h[i] : 0.f;
    }
}

// ---------------- MFMA GEMM (BK=32, 2-buf, 1-deep counted vmcnt) ----------
// Used for Hv (KE=320), L1 (gather, KE=640), L2 (KE=640). 2 blocks/CU.
template <int KE, int GMODE, bool BIAS>
__global__ __launch_bounds__(256, 2) void mfma_gemm(
    const short* __restrict__ Xsrc, const int* __restrict__ wid,
    const short* __restrict__ emb, const short* __restrict__ Wp,
    const float* __restrict__ biasp, short* __restrict__ out)
{
    static_assert(GMODE != 2 || KE == 640, "pair-gather requires KE=640");
    __shared__ __align__(16) short As[2][128 * 32];   // 2 x 8 KB
    __shared__ __align__(16) short Bs[2][320 * 32];   // 2 x 20 KB

    const int tid  = threadIdx.x;
    const int lane = tid & 63;
    const int w    = tid >> 6;
    const int wm   = w >> 1, wn = w & 1;
    const long m0  = (long)blockIdx.x * 128;

    const int s_q   = lane & 3;
    const int r_off = lane >> 2;

    const char* gL[2];
    const char* gR[2];
#pragma unroll
    for (int j = 0; j < 2; ++j) {
        const int r = (w * 2 + j) * 16 + r_off;            // 0..127
        const int q = s_q ^ ((r >> 1) & 3);
        if (GMODE == 2) {
            const long node = m0 + r;
            gL[j] = (const char*)emb + (long)wid[2 * node]     * 640 + q * 16;
            gR[j] = (const char*)emb + (long)wid[2 * node + 1] * 640 + q * 16;
        } else {
            gL[j] = (const char*)Xsrc + (m0 + r) * (long)(KE * 2) + q * 16;
            gR[j] = gL[j];
        }
    }
    const char* gB[5];
#pragma unroll
    for (int j = 0; j < 5; ++j) {
        const int r = (w * 5 + j) * 16 + r_off;            // 0..319
        const int q = s_q ^ ((r >> 1) & 3);
        gB[j] = (const char*)Wp + r * (long)(KE * 2) + q * 16;
    }

    int oA[4];
#pragma unroll
    for (int t = 0; t < 4; ++t) {
        const int row = wm * 64 + t * 16 + (lane & 15);
        const int s   = (lane >> 4) ^ ((row >> 1) & 3);
        oA[t] = row * 32 + s * 8;
    }
    int oB[10];
#pragma unroll
    for (int u = 0; u < 10; ++u) {
        const int n = wn * 160 + u * 16 + (lane & 15);
        const int s = (lane >> 4) ^ ((n >> 1) & 3);
        oB[u] = n * 32 + s * 8;
    }

    auto stage = [&](int buf, int kc) {
        char* baseA = (char*)&As[buf][0];
        char* baseB = (char*)&Bs[buf][0];
        if (GMODE == 2) {
            const bool lft = (kc < 10);
            const int off = (lft ? kc : kc - 10) * 64;
            GLL16((lft ? gL[0] : gR[0]) + off, baseA + (w * 2 + 0) * 1024);
            GLL16((lft ? gL[1] : gR[1]) + off, baseA + (w * 2 + 1) * 1024);
        } else {
            const int off = kc * 64;
            GLL16(gL[0] + off, baseA + (w * 2 + 0) * 1024);
            GLL16(gL[1] + off, baseA + (w * 2 + 1) * 1024);
        }
        const int offb = kc * 64;
#pragma unroll
        for (int j = 0; j < 5; ++j)
            GLL16(gB[j] + offb, baseB + (w * 5 + j) * 1024);
    };

    float4v acc[4][10];
#pragma unroll
    for (int t = 0; t < 4; ++t)
#pragma unroll
        for (int u = 0; u < 10; ++u) acc[t][u] = (float4v)0.f;

    const int NCH = KE / 32;
    stage(0, 0);
    for (int kc = 0; kc < NCH; ++kc) {
        const int cur = kc & 1;
        if (kc + 1 < NCH) {
            stage(cur ^ 1, kc + 1);
            asm volatile("s_waitcnt vmcnt(7)" ::: "memory");
        } else {
            asm volatile("s_waitcnt vmcnt(0)" ::: "memory");
        }
        __builtin_amdgcn_s_barrier();
        __builtin_amdgcn_sched_barrier(0);

        const short* bA = &As[cur][0];
        const short* bB = &Bs[cur][0];
        short8 a[4], b[10];
#pragma unroll
        for (int t = 0; t < 4; ++t) a[t] = *(const short8*)(bA + oA[t]);
#pragma unroll
        for (int u = 0; u < 10; ++u) b[u] = *(const short8*)(bB + oB[u]);
#pragma unroll
        for (int u = 0; u < 10; ++u)
#pragma unroll
            for (int t = 0; t < 4; ++t)
                acc[t][u] = __builtin_amdgcn_mfma_f32_16x16x32_bf16(
                    a[t], b[u], acc[t][u], 0, 0, 0);
        __builtin_amdgcn_s_barrier();
    }

#pragma unroll
    for (int u = 0; u < 10; ++u) {
        const int c = wn * 160 + u * 16 + (lane & 15);
        const float bv = BIAS ? biasp[c] : 0.f;
#pragma unroll
        for (int t = 0; t < 4; ++t) {
            const long mb = m0 + wm * 64 + t * 16 + (lane >> 4) * 4;
#pragma unroll
            for (int r4 = 0; r4 < 4; ++r4)
                out[(mb + r4) * 320 + c] = f2bs(acc[t][u][r4] + bv);
        }
    }
}

// ---------------- per-batch subtree kernel: L3..L8 + classifier -----------
// Root b's subtree depends ONLY on L2 rows [b*128, b*128+128): no cross-block
// communication. One block per batch runs the whole chain in LDS with block
// barriers only — no grid.sync (measured ~25-30us/sync, round 11), no
// intermediate HBM, no extra launches.
//
// Per level (out rows MA, A-rows MA, K=640 in 20 k-planes of 32):
//   - B chunk (320x32, 20 KB) streamed per plane via GLL16 (L2$-broadcast,
//     all 512 blocks read the same bytes).
//   - A read from LDS region in the staged-swizzled layout (verified round 9:
//     value (row,q*8+o) of plane kc lives at [kc*MA*32 + row*32 +
//     (q^((row>>1)&3))*8 + o]).
//   - epilogue writes out row mb, col c into the NEXT level's A region:
//     plane (mb&1)*10+(c>>5), A-row mb>>1, swizzled slot (round-9 formula).
// L3's A is streamed from global (single-plane restage per chunk).
// K-plane order 0..19 == BK=32 chunk order -> bit-identical accumulation.
template<int MA, bool STREAM, bool TOROOTS>
__device__ __forceinline__ void tree_level(
    const int w, const int lane,
    const short* Ain, short* Aout, short* Bs, short* Astage,
    const char* gA, const char* gB0, const char* gB1, const char* gB2,
    const char* gB3, const char* gB4, const float* __restrict__ biasp)
{
    constexpr int MT  = (MA + 15) / 16;     // 4,2,1,1,1,1
    constexpr int TPW = MT * 5;             // tiles per wave (20 nt / 4 waves)
    const int lrow = lane & 15;
    const int hi   = lane >> 4;

    float4v acc[TPW];
#pragma unroll
    for (int t = 0; t < TPW; ++t) acc[t] = (float4v)0.f;

    for (int kc = 0; kc < 20; ++kc) {
        GLL16(gB0 + kc * 64, (char*)Bs + (w * 5 + 0) * 1024);
        GLL16(gB1 + kc * 64, (char*)Bs + (w * 5 + 1) * 1024);
        GLL16(gB2 + kc * 64, (char*)Bs + (w * 5 + 2) * 1024);
        GLL16(gB3 + kc * 64, (char*)Bs + (w * 5 + 3) * 1024);
        GLL16(gB4 + kc * 64, (char*)Bs + (w * 5 + 4) * 1024);
        if (STREAM)
            GLL16(gA + (kc >= 10 ? 640 : 0) + (kc % 10) * 64,
                  (char*)Astage + w * 1024);
        asm volatile("s_waitcnt vmcnt(0)" ::: "memory");
        __builtin_amdgcn_s_barrier();
        __builtin_amdgcn_sched_barrier(0);

#pragma unroll
        for (int t = 0; t < TPW; ++t) {
            const int g  = w + t * 4;
            const int mt = g / 20, nt = g % 20;
            int row = mt * 16 + lrow;
            if (MA < 16) row = (lrow < MA) ? lrow : 0;   // clamp garbage rows
            const int sa = hi ^ ((row >> 1) & 3);
            const short* pa = STREAM
                ? (Astage + row * 32 + sa * 8)
                : (Ain + kc * (MA * 32) + row * 32 + sa * 8);
            const int n  = nt * 16 + lrow;
            const int sb = hi ^ ((n >> 1) & 3);
            const short8 a = *(const short8*)pa;
            const short8 b = *(const short8*)(Bs + n * 32 + sb * 8);
            acc[t] = __builtin_amdgcn_mfma_f32_16x16x32_bf16(
                a, b, acc[t], 0, 0, 0);
        }
        __builtin_amdgcn_s_barrier();     // Bs/Astage reads done before restage
    }

#pragma unroll
    for (int t = 0; t < TPW; ++t) {
        const int g  = w + t * 4;
        const int mt = g / 20, nt = g % 20;
        const int c  = nt * 16 + lrow;
        const float bv = biasp[c];
#pragma unroll
        for (int r4 = 0; r4 < 4; ++r4) {
            const int mb = mt * 16 + hi * 4 + r4;
            if (mb < MA) {
                const short v = f2bs(acc[t][r4] + bv);
                if (TOROOTS) {
                    Aout[mb * 320 + c] = v;
                } else {
                    constexpr int MN = MA / 2;           // next level A-rows
                    const int p  = (mb & 1) * 10 + (c >> 5);
                    const int m2 = mb >> 1;
                    const int q  = (c >> 3) & 3;
                    Aout[p * (MN * 32) + m2 * 32 +
                         (q ^ ((m2 >> 1) & 3)) * 8 + (c & 7)] = v;
                }
            }
        }
    }
    __syncthreads();   // next-A visible to all waves before next level
}

__global__ __launch_bounds__(256, 2) void subtree(
    const short* __restrict__ L2in, const short* __restrict__ Wp,
    const float* __restrict__ biasp, const float* __restrict__ W_cls,
    const float* __restrict__ b_cls, float* __restrict__ outp)
{
    __shared__ __align__(16) short Bs[320 * 32];      // 20 KB (one k-plane)
    __shared__ __align__(16) short AX[20 * 32 * 32];  // 40 KB
    __shared__ __align__(16) short AY[10240];         // 20 KB  => 80 KB total

    const int tid  = threadIdx.x;
    const int lane = tid & 63;
    const int w    = tid >> 6;
    const int s_q   = lane & 3;
    const int r_off = lane >> 2;
    const long base = (long)blockIdx.x * 128;         // this batch's L2 rows

    const char* gB[5];
#pragma unroll
    for (int j = 0; j < 5; ++j) {
        const int r = (w * 5 + j) * 16 + r_off;       // 0..319
        const int q = s_q ^ ((r >> 1) & 3);
        gB[j] = (const char*)Wp + r * 1280L + q * 16;
    }
    // L3 A-stream base: A-row rS = concat(L2[base+2rS], L2[base+2rS+1])
    const int rS = w * 16 + r_off;                    // 0..63
    const int qS = s_q ^ ((rS >> 1) & 3);
    const char* gA3 = (const char*)L2in + (base + 2 * rS) * 640 + qS * 16;

    // L3: 64 rows (A streamed, staged per-chunk in AY) -> L4A in AX
    tree_level<64, true,  false>(w, lane, nullptr, AX, Bs, AY, gA3,
                                 gB[0], gB[1], gB[2], gB[3], gB[4], biasp);
    // L4: 32 rows (A=AX) -> L5A in AY
    tree_level<32, false, false>(w, lane, AX, AY, Bs, nullptr, nullptr,
                                 gB[0], gB[1], gB[2], gB[3], gB[4], biasp);
    // L5: 16 -> AX
    tree_level<16, false, false>(w, lane, AY, AX, Bs, nullptr, nullptr,
                                 gB[0], gB[1], gB[2], gB[3], gB[4], biasp);
    // L6: 8 -> AY
    tree_level<8,  false, false>(w, lane, AX, AY, Bs, nullptr, nullptr,
                                 gB[0], gB[1], gB[2], gB[3], gB[4], biasp);
    // L7: 4 -> AX
    tree_level<4,  false, false>(w, lane, AY, AX, Bs, nullptr, nullptr,
                                 gB[0], gB[1], gB[2], gB[3], gB[4], biasp);
    // L8: 2 roots (plain 2x320) -> AY
    tree_level<2,  false, true >(w, lane, AX, AY, Bs, nullptr, nullptr,
                                 gB[0], gB[1], gB[2], gB[3], gB[4], biasp);

    // classifier for batch blockIdx.x: feat = sigmoid(concat(root0, root1))
    if (w == 0) {
        float a0 = 0.f, a1 = 0.f, a2 = 0.f;
#pragma unroll
        for (int i = 0; i < 10; ++i) {
            const int k = lane + 64 * i;
            if (k < 600) {
                const int col = (k < 300) ? k : (320 + k - 300);
                const float f = 1.f / (1.f + __expf(-bs2f(AY[col])));
                a0 += f * W_cls[k];
                a1 += f * W_cls[600 + k];
                a2 += f * W_cls[1200 + k];
            }
        }
#pragma unroll
        for (int off = 32; off > 0; off >>= 1) {
            a0 += __shfl_down(a0, off);
            a1 += __shfl_down(a1, off);
            a2 += __shfl_down(a2, off);
        }
        if (lane == 0) {
            const int b = blockIdx.x;
            const float l0 = a0 + b_cls[0];
            const float l1 = a1 + b_cls[1];
            const float l2 = a2 + b_cls[2];
            const float m  = fmaxf(l0, fmaxf(l1, l2));
            const float s  = __expf(l0 - m) + __expf(l1 - m) + __expf(l2 - m);
            const float ls = m + __logf(s);
            outp[b * 3 + 0] = l0 - ls;
            outp[b * 3 + 1] = l1 - ls;
            outp[b * 3 + 2] = l2 - ls;
        }
    }
}

extern "C" void kernel_launch(void* const* d_in, const int* in_sizes, int n_in,
                              void* d_out, int out_size, void* d_ws, size_t ws_size,
                              hipStream_t stream)
{
    const int*   wid    = (const int*)d_in[0];     // (512,2,256) int32
    const float* emb    = (const float*)d_in[1];   // (50000,300) f32
    const float* W_leaf = (const float*)d_in[2];   // (300,300)
    const float* W_h    = (const float*)d_in[3];   // (300,600)
    const float* b_h    = (const float*)d_in[4];   // (300,)
    const float* W_cls  = (const float*)d_in[5];   // (3,600)
    const float* b_cls  = (const float*)d_in[6];   // (3,)
    float* outp = (float*)d_out;                   // (512,3) f32

    (void)in_sizes; (void)n_in; (void)out_size; (void)ws_size;

    // ws layout (peak 158,557,440 B):
    //   bufA   @ 0           : 131072*320*2 =  83,886,080  (L1 out)
    //   bufB   @  83,886,080 :  65536*320*2 =  41,943,040  (L2 out)
    //   emb_bf @  83,886,080 : 50176*320*2  =  32,112,640  (ALIASES bufB: dead
    //            after Hv GEMM; bufB first written by L2, which runs later)
    //   Hv     @ 125,829,120 : 50176*320*2  =  32,112,640
    //   Bleaf  @ 157,941,760 : 320*320*2    =     204,800
    //   Bh     @ 158,146,560 : 320*640*2    =     409,600
    //   biasp  @ 158,556,160 : 320*4        =       1,280
    char* ws = (char*)d_ws;
    short* bufA   = (short*)(ws);
    short* bufB   = (short*)(ws + 83886080);
    short* emb_bf = (short*)(ws + 83886080);
    short* Hv     = (short*)(ws + 125829120);
    short* Bleaf  = (short*)(ws + 157941760);
    short* Bh     = (short*)(ws + 158146560);
    float* biasp  = (float*)(ws + 158556160);

    conv_emb<<<(50176 * 80) / 256, 256, 0, stream>>>(emb, emb_bf);
    conv_w  <<<(307520 + 255) / 256, 256, 0, stream>>>(
        W_h, W_leaf, b_h, Bh, Bleaf, biasp);

    // Vocab-level leaf transform: Hv = emb_bf @ Bleaf^T, M=50176.
    mfma_gemm<320, 0, false><<<50176 / 128, 256, 0, stream>>>(
        emb_bf, nullptr, nullptr, Bleaf, biasp, Hv);

    // L1: node m = W_h @ concat(Hv[wid[2m]], Hv[wid[2m+1]]) + b_h -> bufA.
    mfma_gemm<640, 2, true><<<131072 / 128, 256, 0, stream>>>(
        nullptr, wid, Hv, Bh, biasp, bufA);

    // L2: throughput GEMM, 512 blocks (2/CU): bufA -> bufB (65536 rows).
    mfma_gemm<640, 0, true><<<65536 / 128, 256, 0, stream>>>(
        bufA, nullptr, nullptr, Bh, biasp, bufB);

    // L3..L8 + classifier: one block per batch, fully in-LDS, one launch.
    subtree<<<512, 256, 0, stream>>>(bufB, Bh, biasp, W_cls, b_cls, outp);
}

// Round 15
// 304.038 us; speedup vs baseline: 1.8540x; 1.1308x over previous
//
#include <hip/hip_runtime.h>
#include <hip/hip_bf16.h>

typedef __hip_bfloat16 bf16;
typedef __attribute__((ext_vector_type(8))) short short8;   // 8 bf16 = 4 VGPRs
typedef __attribute__((ext_vector_type(4))) float float4v;  // MFMA C/D
typedef __attribute__((ext_vector_type(4))) short short4v;

__device__ __forceinline__ short f2bs(float x) {
    bf16 b = __float2bfloat16(x);
    return *reinterpret_cast<short*>(&b);
}
__device__ __forceinline__ float bs2f(short s) {
    bf16 b = *reinterpret_cast<bf16*>(&s);
    return __bfloat162float(b);
}

#define GLL16(g, l) __builtin_amdgcn_global_load_lds(                      \
    (const __attribute__((address_space(1))) void*)(g),                    \
    (__attribute__((address_space(3))) void*)(l), 16, 0, 0)

// ---------------- fused preprocessing: one kernel, region-split -----------
// Region A (idx < 4,014,080 = 50176*80): emb f32 -> emb_bf (50176,320) bf16,
//   float4 loads, 4 shorts/thread. Region boundary is block-aligned
//   (4014080/256 = 15680) -> no intra-block divergence.
// Region B: W_h -> Bh (320x640), W_leaf -> Bleaf (320x320), b_h -> biasp.
__global__ __launch_bounds__(256) void conv_all(
    const float* __restrict__ emb, const float* __restrict__ W_h,
    const float* __restrict__ W_leaf, const float* __restrict__ b_h,
    short* __restrict__ emb_bf, short* __restrict__ Bh,
    short* __restrict__ Bleaf, float* __restrict__ biasp)
{
    const int idx = blockIdx.x * 256 + threadIdx.x;
    if (idx < 4014080) {                                  // emb region
        const int row = idx / 80;
        const int k4  = (idx - row * 80) * 4;
        short4v v = (short4v)0;
        if (row < 50000 && k4 < 300) {
            const float4v f = *reinterpret_cast<const float4v*>(
                emb + (long)row * 300 + k4);
#pragma unroll
            for (int j = 0; j < 4; ++j) v[j] = f2bs(f[j]);
        }
        *(short4v*)&emb_bf[(long)row * 320 + k4] = v;
        return;
    }
    const int j = idx - 4014080;
    if (j < 204800) {                                     // Bh 320x640
        const int row = j / 640, k = j - row * 640;
        float v = 0.f;
        if (row < 300) {
            if (k < 300)                  v = W_h[row * 600 + k];
            else if (k >= 320 && k < 620) v = W_h[row * 600 + k - 20];
        }
        Bh[j] = f2bs(v);
    } else if (j < 307200) {                              // Bleaf 320x320
        const int i = j - 204800;
        const int row = i / 320, k = i - row * 320;
        Bleaf[i] = (row < 300 && k < 300) ? f2bs(W_leaf[row * 300 + k])
                                          : (short)0;
    } else if (j < 307520) {                              // biasp 320
        const int i = j - 307200;
        biasp[i] = (i < 300) ? b_h[i] : 0.f;
    }
}

// ---------------- MFMA GEMM (BK=32, 2-buf, 1-deep counted vmcnt) ----------
// Used for Hv (KE=320), L1 (gather, KE=640), L2 (KE=640). 2 blocks/CU.
template <int KE, int GMODE, bool BIAS>
__global__ __launch_bounds__(256, 2) void mfma_gemm(
    const short* __restrict__ Xsrc, const int* __restrict__ wid,
    const short* __restrict__ emb, const short* __restrict__ Wp,
    const float* __restrict__ biasp, short* __restrict__ out)
{
    static_assert(GMODE != 2 || KE == 640, "pair-gather requires KE=640");
    __shared__ __align__(16) short As[2][128 * 32];   // 2 x 8 KB
    __shared__ __align__(16) short Bs[2][320 * 32];   // 2 x 20 KB

    const int tid  = threadIdx.x;
    const int lane = tid & 63;
    const int w    = tid >> 6;
    const int wm   = w >> 1, wn = w & 1;
    const long m0  = (long)blockIdx.x * 128;

    const int s_q   = lane & 3;
    const int r_off = lane >> 2;

    const char* gL[2];
    const char* gR[2];
#pragma unroll
    for (int j = 0; j < 2; ++j) {
        const int r = (w * 2 + j) * 16 + r_off;            // 0..127
        const int q = s_q ^ ((r >> 1) & 3);
        if (GMODE == 2) {
            const long node = m0 + r;
            gL[j] = (const char*)emb + (long)wid[2 * node]     * 640 + q * 16;
            gR[j] = (const char*)emb + (long)wid[2 * node + 1] * 640 + q * 16;
        } else {
            gL[j] = (const char*)Xsrc + (m0 + r) * (long)(KE * 2) + q * 16;
            gR[j] = gL[j];
        }
    }
    const char* gB[5];
#pragma unroll
    for (int j = 0; j < 5; ++j) {
        const int r = (w * 5 + j) * 16 + r_off;            // 0..319
        const int q = s_q ^ ((r >> 1) & 3);
        gB[j] = (const char*)Wp + r * (long)(KE * 2) + q * 16;
    }

    int oA[4];
#pragma unroll
    for (int t = 0; t < 4; ++t) {
        const int row = wm * 64 + t * 16 + (lane & 15);
        const int s   = (lane >> 4) ^ ((row >> 1) & 3);
        oA[t] = row * 32 + s * 8;
    }
    int oB[10];
#pragma unroll
    for (int u = 0; u < 10; ++u) {
        const int n = wn * 160 + u * 16 + (lane & 15);
        const int s = (lane >> 4) ^ ((n >> 1) & 3);
        oB[u] = n * 32 + s * 8;
    }

    auto stage = [&](int buf, int kc) {
        char* baseA = (char*)&As[buf][0];
        char* baseB = (char*)&Bs[buf][0];
        if (GMODE == 2) {
            const bool lft = (kc < 10);
            const int off = (lft ? kc : kc - 10) * 64;
            GLL16((lft ? gL[0] : gR[0]) + off, baseA + (w * 2 + 0) * 1024);
            GLL16((lft ? gL[1] : gR[1]) + off, baseA + (w * 2 + 1) * 1024);
        } else {
            const int off = kc * 64;
            GLL16(gL[0] + off, baseA + (w * 2 + 0) * 1024);
            GLL16(gL[1] + off, baseA + (w * 2 + 1) * 1024);
        }
        const int offb = kc * 64;
#pragma unroll
        for (int j = 0; j < 5; ++j)
            GLL16(gB[j] + offb, baseB + (w * 5 + j) * 1024);
    };

    float4v acc[4][10];
#pragma unroll
    for (int t = 0; t < 4; ++t)
#pragma unroll
        for (int u = 0; u < 10; ++u) acc[t][u] = (float4v)0.f;

    const int NCH = KE / 32;
    stage(0, 0);
    for (int kc = 0; kc < NCH; ++kc) {
        const int cur = kc & 1;
        if (kc + 1 < NCH) {
            stage(cur ^ 1, kc + 1);
            asm volatile("s_waitcnt vmcnt(7)" ::: "memory");
        } else {
            asm volatile("s_waitcnt vmcnt(0)" ::: "memory");
        }
        __builtin_amdgcn_s_barrier();
        __builtin_amdgcn_sched_barrier(0);

        const short* bA = &As[cur][0];
        const short* bB = &Bs[cur][0];
        short8 a[4], b[10];
#pragma unroll
        for (int t = 0; t < 4; ++t) a[t] = *(const short8*)(bA + oA[t]);
#pragma unroll
        for (int u = 0; u < 10; ++u) b[u] = *(const short8*)(bB + oB[u]);
#pragma unroll
        for (int u = 0; u < 10; ++u)
#pragma unroll
            for (int t = 0; t < 4; ++t)
                acc[t][u] = __builtin_amdgcn_mfma_f32_16x16x32_bf16(
                    a[t], b[u], acc[t][u], 0, 0, 0);
        __builtin_amdgcn_s_barrier();
    }

#pragma unroll
    for (int u = 0; u < 10; ++u) {
        const int c = wn * 160 + u * 16 + (lane & 15);
        const float bv = BIAS ? biasp[c] : 0.f;
#pragma unroll
        for (int t = 0; t < 4; ++t) {
            const long mb = m0 + wm * 64 + t * 16 + (lane >> 4) * 4;
#pragma unroll
            for (int r4 = 0; r4 < 4; ++r4)
                out[(mb + r4) * 320 + c] = f2bs(acc[t][u][r4] + bv);
        }
    }
}

// ---------------- per-CU dual-batch subtree: L3..L8 + classifier ----------
// Round-14 subtree measured 123 us: per-CU L2->CU delivery bound (each block
// pulls B 20KB + A 4KB per plane-iter; 2 blocks/CU = 48KB/iter through the
// ~64B/cy L2 port). Fix: ONE 512-thread block per CU handles TWO batches —
// B staged once per plane now feeds both batches (delivery/iter ~halved).
// Waves 0-3: stage B + compute batch 0; waves 4-7: stage L3 A-streams (both
// batches) + compute batch 1. Identical per-batch arithmetic (wl=w&3
// replaces w in all formulas) -> bit-identical results.
template<int MA, bool STREAM, bool TOROOTS>
__device__ __forceinline__ void tree_level(
    const int w, const int wl, const int lane,
    const short* Ain, short* Aout, short* Bs,
    const short* myAst, short* Ast0, short* Ast1,
    const char* gA0, const char* gA1,
    const char* gB0, const char* gB1, const char* gB2,
    const char* gB3, const char* gB4, const float* __restrict__ biasp)
{
    constexpr int MT  = (MA + 15) / 16;     // 4,2,1,1,1,1
    constexpr int TPW = MT * 5;             // tiles per 4-wave group
    const int lrow = lane & 15;
    const int hi   = lane >> 4;

    float4v acc[TPW];
#pragma unroll
    for (int t = 0; t < TPW; ++t) acc[t] = (float4v)0.f;

    for (int kc = 0; kc < 20; ++kc) {
        if (w < 4) {                        // waves 0-3: B plane (shared)
            GLL16(gB0 + kc * 64, (char*)Bs + (w * 5 + 0) * 1024);
            GLL16(gB1 + kc * 64, (char*)Bs + (w * 5 + 1) * 1024);
            GLL16(gB2 + kc * 64, (char*)Bs + (w * 5 + 2) * 1024);
            GLL16(gB3 + kc * 64, (char*)Bs + (w * 5 + 3) * 1024);
            GLL16(gB4 + kc * 64, (char*)Bs + (w * 5 + 4) * 1024);
        } else if (STREAM) {                // waves 4-7: both A-streams
            const int off = (kc >= 10 ? 640 : 0) + (kc % 10) * 64;
            GLL16(gA0 + off, (char*)Ast0 + (w - 4) * 1024);
            GLL16(gA1 + off, (char*)Ast1 + (w - 4) * 1024);
        }
        asm volatile("s_waitcnt vmcnt(0)" ::: "memory");
        __builtin_amdgcn_s_barrier();
        __builtin_amdgcn_sched_barrier(0);

#pragma unroll
        for (int t = 0; t < TPW; ++t) {
            const int g  = wl + t * 4;
            const int mt = g / 20, nt = g % 20;
            int row = mt * 16 + lrow;
            if (MA < 16) row = (lrow < MA) ? lrow : 0;   // clamp garbage rows
            const int sa = hi ^ ((row >> 1) & 3);
            const short* pa = STREAM
                ? (myAst + row * 32 + sa * 8)
                : (Ain + kc * (MA * 32) + row * 32 + sa * 8);
            const int n  = nt * 16 + lrow;
            const int sb = hi ^ ((n >> 1) & 3);
            const short8 a = *(const short8*)pa;
            const short8 b = *(const short8*)(Bs + n * 32 + sb * 8);
            acc[t] = __builtin_amdgcn_mfma_f32_16x16x32_bf16(
                a, b, acc[t], 0, 0, 0);
        }
        __builtin_amdgcn_s_barrier();     // reads done before next restage
    }

#pragma unroll
    for (int t = 0; t < TPW; ++t) {
        const int g  = wl + t * 4;
        const int mt = g / 20, nt = g % 20;
        const int c  = nt * 16 + lrow;
        const float bv = biasp[c];
#pragma unroll
        for (int r4 = 0; r4 < 4; ++r4) {
            const int mb = mt * 16 + hi * 4 + r4;
            if (mb < MA) {
                const short v = f2bs(acc[t][r4] + bv);
                if (TOROOTS) {
                    Aout[mb * 320 + c] = v;
                } else {
                    constexpr int MN = MA / 2;           // next level A-rows
                    const int p  = (mb & 1) * 10 + (c >> 5);
                    const int m2 = mb >> 1;
                    const int q  = (c >> 3) & 3;
                    Aout[p * (MN * 32) + m2 * 32 +
                         (q ^ ((m2 >> 1) & 3)) * 8 + (c & 7)] = v;
                }
            }
        }
    }
    __syncthreads();   // next-A visible to all waves before next level
}

__global__ __launch_bounds__(512, 1) void subtree(
    const short* __restrict__ L2in, const short* __restrict__ Wp,
    const float* __restrict__ biasp, const float* __restrict__ W_cls,
    const float* __restrict__ b_cls, float* __restrict__ outp)
{
    __shared__ __align__(16) short Bs[320 * 32];        // 20 KB (shared)
    __shared__ __align__(16) short AXs[2][20 * 32 * 32];// 2 x 40 KB
    __shared__ __align__(16) short AYs[2][10240];       // 2 x 20 KB
    __shared__ __align__(16) short Ast[2][2048];        // 2 x 4 KB => 148 KB

    const int tid  = threadIdx.x;
    const int lane = tid & 63;
    const int w    = tid >> 6;            // 0..7
    const int wl   = w & 3;               // wave within group
    const int grp  = w >> 2;              // batch group 0/1
    const int s_q   = lane & 3;
    const int r_off = lane >> 2;

    const char* gB[5];
#pragma unroll
    for (int j = 0; j < 5; ++j) {
        const int r = (wl * 5 + j) * 16 + r_off;      // 0..319 (used by w<4)
        const int q = s_q ^ ((r >> 1) & 3);
        gB[j] = (const char*)Wp + r * 1280L + q * 16;
    }
    // L3 A-stream bases (used by waves 4-7, one GLL per batch)
    const int wa = (w >= 4) ? (w - 4) : 0;
    const int rS = wa * 16 + r_off;                   // 0..63
    const int qS = s_q ^ ((rS >> 1) & 3);
    const long base0 = (long)(2 * blockIdx.x) * 128;
    const char* gA0 = (const char*)L2in + (base0 + 2 * rS) * 640 + qS * 16;
    const char* gA1 = (const char*)L2in + (base0 + 128 + 2 * rS) * 640 + qS * 16;

    short* AXm = AXs[grp];
    short* AYm = AYs[grp];

    // L3: 64 rows (A streamed into Ast[grp]) -> L4A in AXm
    tree_level<64, true,  false>(w, wl, lane, nullptr, AXm, Bs,
                                 Ast[grp], Ast[0], Ast[1], gA0, gA1,
                                 gB[0], gB[1], gB[2], gB[3], gB[4], biasp);
    // L4: 32 -> AYm
    tree_level<32, false, false>(w, wl, lane, AXm, AYm, Bs,
                                 nullptr, nullptr, nullptr, nullptr, nullptr,
                                 gB[0], gB[1], gB[2], gB[3], gB[4], biasp);
    // L5: 16 -> AXm
    tree_level<16, false, false>(w, wl, lane, AYm, AXm, Bs,
                                 nullptr, nullptr, nullptr, nullptr, nullptr,
                                 gB[0], gB[1], gB[2], gB[3], gB[4], biasp);
    // L6: 8 -> AYm
    tree_level<8,  false, false>(w, wl, lane, AXm, AYm, Bs,
                                 nullptr, nullptr, nullptr, nullptr, nullptr,
                                 gB[0], gB[1], gB[2], gB[3], gB[4], biasp);
    // L7: 4 -> AXm
    tree_level<4,  false, false>(w, wl, lane, AYm, AXm, Bs,
                                 nullptr, nullptr, nullptr, nullptr, nullptr,
                                 gB[0], gB[1], gB[2], gB[3], gB[4], biasp);
    // L8: 2 roots (plain 2x320) -> AYm
    tree_level<2,  false, true >(w, wl, lane, AXm, AYm, Bs,
                                 nullptr, nullptr, nullptr, nullptr, nullptr,
                                 gB[0], gB[1], gB[2], gB[3], gB[4], biasp);

    // classifier: wave 0 -> batch 2*blk, wave 4 -> batch 2*blk+1
    if (wl == 0) {
        const short* rowp = AYs[grp];
        float a0 = 0.f, a1 = 0.f, a2 = 0.f;
#pragma unroll
        for (int i = 0; i < 10; ++i) {
            const int k = lane + 64 * i;
            if (k < 600) {
                const int col = (k < 300) ? k : (320 + k - 300);
                const float f = 1.f / (1.f + __expf(-bs2f(rowp[col])));
                a0 += f * W_cls[k];
                a1 += f * W_cls[600 + k];
                a2 += f * W_cls[1200 + k];
            }
        }
#pragma unroll
        for (int off = 32; off > 0; off >>= 1) {
            a0 += __shfl_down(a0, off);
            a1 += __shfl_down(a1, off);
            a2 += __shfl_down(a2, off);
        }
        if (lane == 0) {
            const int b = blockIdx.x * 2 + grp;
            const float l0 = a0 + b_cls[0];
            const float l1 = a1 + b_cls[1];
            const float l2 = a2 + b_cls[2];
            const float m  = fmaxf(l0, fmaxf(l1, l2));
            const float s  = __expf(l0 - m) + __expf(l1 - m) + __expf(l2 - m);
            const float ls = m + __logf(s);
            outp[b * 3 + 0] = l0 - ls;
            outp[b * 3 + 1] = l1 - ls;
            outp[b * 3 + 2] = l2 - ls;
        }
    }
}

extern "C" void kernel_launch(void* const* d_in, const int* in_sizes, int n_in,
                              void* d_out, int out_size, void* d_ws, size_t ws_size,
                              hipStream_t stream)
{
    const int*   wid    = (const int*)d_in[0];     // (512,2,256) int32
    const float* emb    = (const float*)d_in[1];   // (50000,300) f32
    const float* W_leaf = (const float*)d_in[2];   // (300,300)
    const float* W_h    = (const float*)d_in[3];   // (300,600)
    const float* b_h    = (const float*)d_in[4];   // (300,)
    const float* W_cls  = (const float*)d_in[5];   // (3,600)
    const float* b_cls  = (const float*)d_in[6];   // (3,)
    float* outp = (float*)d_out;                   // (512,3) f32

    (void)in_sizes; (void)n_in; (void)out_size; (void)ws_size;

    // ws layout (peak 158,557,440 B):
    //   bufA   @ 0           : 131072*320*2 =  83,886,080  (L1 out)
    //   bufB   @  83,886,080 :  65536*320*2 =  41,943,040  (L2 out)
    //   emb_bf @  83,886,080 : 50176*320*2  =  32,112,640  (ALIASES bufB: dead
    //            after Hv GEMM; bufB first written by L2, which runs later)
    //   Hv     @ 125,829,120 : 50176*320*2  =  32,112,640
    //   Bleaf  @ 157,941,760 : 320*320*2    =     204,800
    //   Bh     @ 158,146,560 : 320*640*2    =     409,600
    //   biasp  @ 158,556,160 : 320*4        =       1,280
    char* ws = (char*)d_ws;
    short* bufA   = (short*)(ws);
    short* bufB   = (short*)(ws + 83886080);
    short* emb_bf = (short*)(ws + 83886080);
    short* Hv     = (short*)(ws + 125829120);
    short* Bleaf  = (short*)(ws + 157941760);
    short* Bh     = (short*)(ws + 158146560);
    float* biasp  = (float*)(ws + 158556160);

    // fused preprocessing: 4,321,600 work items
    conv_all<<<(4321600 + 255) / 256, 256, 0, stream>>>(
        emb, W_h, W_leaf, b_h, emb_bf, Bh, Bleaf, biasp);

    // Vocab-level leaf transform: Hv = emb_bf @ Bleaf^T, M=50176.
    mfma_gemm<320, 0, false><<<50176 / 128, 256, 0, stream>>>(
        emb_bf, nullptr, nullptr, Bleaf, biasp, Hv);

    // L1: node m = W_h @ concat(Hv[wid[2m]], Hv[wid[2m+1]]) + b_h -> bufA.
    mfma_gemm<640, 2, true><<<131072 / 128, 256, 0, stream>>>(
        nullptr, wid, Hv, Bh, biasp, bufA);

    // L2: throughput GEMM, 512 blocks (2/CU): bufA -> bufB (65536 rows).
    mfma_gemm<640, 0, true><<<65536 / 128, 256, 0, stream>>>(
        bufA, nullptr, nullptr, Bh, biasp, bufB);

    // L3..L8 + classifier: 256 blocks (1/CU), 2 batches/block, B shared.
    subtree<<<256, 512, 0, stream>>>(bufB, Bh, biasp, W_cls, b_cls, outp);
}

// Round 16
// 293.455 us; speedup vs baseline: 1.9208x; 1.0361x over previous
//
#include <hip/hip_runtime.h>
#include <hip/hip_bf16.h>

typedef __hip_bfloat16 bf16;
typedef __attribute__((ext_vector_type(8))) short short8;   // 8 bf16 = 4 VGPRs
typedef __attribute__((ext_vector_type(4))) float float4v;  // MFMA C/D
typedef __attribute__((ext_vector_type(4))) short short4v;

__device__ __forceinline__ short f2bs(float x) {
    bf16 b = __float2bfloat16(x);
    return *reinterpret_cast<short*>(&b);
}
__device__ __forceinline__ float bs2f(short s) {
    bf16 b = *reinterpret_cast<bf16*>(&s);
    return __bfloat162float(b);
}

#define GLL16(g, l) __builtin_amdgcn_global_load_lds(                      \
    (const __attribute__((address_space(1))) void*)(g),                    \
    (__attribute__((address_space(3))) void*)(l), 16, 0, 0)

// ---------------- fused preprocessing: one kernel, region-split -----------
__global__ __launch_bounds__(256) void conv_all(
    const float* __restrict__ emb, const float* __restrict__ W_h,
    const float* __restrict__ W_leaf, const float* __restrict__ b_h,
    short* __restrict__ emb_bf, short* __restrict__ Bh,
    short* __restrict__ Bleaf, float* __restrict__ biasp)
{
    const int idx = blockIdx.x * 256 + threadIdx.x;
    if (idx < 4014080) {                                  // emb region
        const int row = idx / 80;
        const int k4  = (idx - row * 80) * 4;
        short4v v = (short4v)0;
        if (row < 50000 && k4 < 300) {
            const float4v f = *reinterpret_cast<const float4v*>(
                emb + (long)row * 300 + k4);
#pragma unroll
            for (int j = 0; j < 4; ++j) v[j] = f2bs(f[j]);
        }
        *(short4v*)&emb_bf[(long)row * 320 + k4] = v;
        return;
    }
    const int j = idx - 4014080;
    if (j < 204800) {                                     // Bh 320x640
        const int row = j / 640, k = j - row * 640;
        float v = 0.f;
        if (row < 300) {
            if (k < 300)                  v = W_h[row * 600 + k];
            else if (k >= 320 && k < 620) v = W_h[row * 600 + k - 20];
        }
        Bh[j] = f2bs(v);
    } else if (j < 307200) {                              // Bleaf 320x320
        const int i = j - 204800;
        const int row = i / 320, k = i - row * 320;
        Bleaf[i] = (row < 300 && k < 300) ? f2bs(W_leaf[row * 300 + k])
                                          : (short)0;
    } else if (j < 307520) {                              // biasp 320
        const int i = j - 307200;
        biasp[i] = (i < 300) ? b_h[i] : 0.f;
    }
}

// ---------------- MFMA GEMM (BK=32, 2-buf, 1-deep counted vmcnt) ----------
// Used for Hv (KE=320), L1 (gather, KE=640), L2 (KE=640). 2 blocks/CU.
template <int KE, int GMODE, bool BIAS>
__global__ __launch_bounds__(256, 2) void mfma_gemm(
    const short* __restrict__ Xsrc, const int* __restrict__ wid,
    const short* __restrict__ emb, const short* __restrict__ Wp,
    const float* __restrict__ biasp, short* __restrict__ out)
{
    static_assert(GMODE != 2 || KE == 640, "pair-gather requires KE=640");
    __shared__ __align__(16) short As[2][128 * 32];   // 2 x 8 KB
    __shared__ __align__(16) short Bs[2][320 * 32];   // 2 x 20 KB

    const int tid  = threadIdx.x;
    const int lane = tid & 63;
    const int w    = tid >> 6;
    const int wm   = w >> 1, wn = w & 1;
    const long m0  = (long)blockIdx.x * 128;

    const int s_q   = lane & 3;
    const int r_off = lane >> 2;

    const char* gL[2];
    const char* gR[2];
#pragma unroll
    for (int j = 0; j < 2; ++j) {
        const int r = (w * 2 + j) * 16 + r_off;            // 0..127
        const int q = s_q ^ ((r >> 1) & 3);
        if (GMODE == 2) {
            const long node = m0 + r;
            gL[j] = (const char*)emb + (long)wid[2 * node]     * 640 + q * 16;
            gR[j] = (const char*)emb + (long)wid[2 * node + 1] * 640 + q * 16;
        } else {
            gL[j] = (const char*)Xsrc + (m0 + r) * (long)(KE * 2) + q * 16;
            gR[j] = gL[j];
        }
    }
    const char* gB[5];
#pragma unroll
    for (int j = 0; j < 5; ++j) {
        const int r = (w * 5 + j) * 16 + r_off;            // 0..319
        const int q = s_q ^ ((r >> 1) & 3);
        gB[j] = (const char*)Wp + r * (long)(KE * 2) + q * 16;
    }

    int oA[4];
#pragma unroll
    for (int t = 0; t < 4; ++t) {
        const int row = wm * 64 + t * 16 + (lane & 15);
        const int s   = (lane >> 4) ^ ((row >> 1) & 3);
        oA[t] = row * 32 + s * 8;
    }
    int oB[10];
#pragma unroll
    for (int u = 0; u < 10; ++u) {
        const int n = wn * 160 + u * 16 + (lane & 15);
        const int s = (lane >> 4) ^ ((n >> 1) & 3);
        oB[u] = n * 32 + s * 8;
    }

    auto stage = [&](int buf, int kc) {
        char* baseA = (char*)&As[buf][0];
        char* baseB = (char*)&Bs[buf][0];
        if (GMODE == 2) {
            const bool lft = (kc < 10);
            const int off = (lft ? kc : kc - 10) * 64;
            GLL16((lft ? gL[0] : gR[0]) + off, baseA + (w * 2 + 0) * 1024);
            GLL16((lft ? gL[1] : gR[1]) + off, baseA + (w * 2 + 1) * 1024);
        } else {
            const int off = kc * 64;
            GLL16(gL[0] + off, baseA + (w * 2 + 0) * 1024);
            GLL16(gL[1] + off, baseA + (w * 2 + 1) * 1024);
        }
        const int offb = kc * 64;
#pragma unroll
        for (int j = 0; j < 5; ++j)
            GLL16(gB[j] + offb, baseB + (w * 5 + j) * 1024);
    };

    float4v acc[4][10];
#pragma unroll
    for (int t = 0; t < 4; ++t)
#pragma unroll
        for (int u = 0; u < 10; ++u) acc[t][u] = (float4v)0.f;

    const int NCH = KE / 32;
    stage(0, 0);
    for (int kc = 0; kc < NCH; ++kc) {
        const int cur = kc & 1;
        if (kc + 1 < NCH) {
            stage(cur ^ 1, kc + 1);
            asm volatile("s_waitcnt vmcnt(7)" ::: "memory");
        } else {
            asm volatile("s_waitcnt vmcnt(0)" ::: "memory");
        }
        __builtin_amdgcn_s_barrier();
        __builtin_amdgcn_sched_barrier(0);

        const short* bA = &As[cur][0];
        const short* bB = &Bs[cur][0];
        short8 a[4], b[10];
#pragma unroll
        for (int t = 0; t < 4; ++t) a[t] = *(const short8*)(bA + oA[t]);
#pragma unroll
        for (int u = 0; u < 10; ++u) b[u] = *(const short8*)(bB + oB[u]);
#pragma unroll
        for (int u = 0; u < 10; ++u)
#pragma unroll
            for (int t = 0; t < 4; ++t)
                acc[t][u] = __builtin_amdgcn_mfma_f32_16x16x32_bf16(
                    a[t], b[u], acc[t][u], 0, 0, 0);
        __builtin_amdgcn_s_barrier();
    }

#pragma unroll
    for (int u = 0; u < 10; ++u) {
        const int c = wn * 160 + u * 16 + (lane & 15);
        const float bv = BIAS ? biasp[c] : 0.f;
#pragma unroll
        for (int t = 0; t < 4; ++t) {
            const long mb = m0 + wm * 64 + t * 16 + (lane >> 4) * 4;
#pragma unroll
            for (int r4 = 0; r4 < 4; ++r4)
                out[(mb + r4) * 320 + c] = f2bs(acc[t][u][r4] + bv);
        }
    }
}

// ---------------- per-CU dual-batch subtree: L3..L8 + classifier ----------
// Round-15: 84 us, latency-bound (vmcnt(0) each of 120 plane-iters exposes
// the full L2 round trip; compute/iter is only ~100-300cy). This round:
// double-buffer Bs + the L3 A-stage ring with the proven counted-vmcnt loop
// (B-waves wait vmcnt(5), L3 A-waves vmcnt(2), never 0 mid-loop).
// LDS = Bs 2x20 + AX 2x40 + AY 2x20 = 160 KiB exactly; the L3 A-stage ring
// (2 x 4 KB per batch) lives in AY, which is free during L3 (round-14
// pattern). Buffer chain: L3:AYstage->AX, L4:AX->AY, L5:AY->AX, L6:AX->AY,
// L7:AY->AX, L8:AX->AY(roots). Same arithmetic order -> bit-identical.
template<int MA, bool STREAM, bool TOROOTS>
__device__ __forceinline__ void tree_level(
    const int w, const int wl, const int lane,
    const short* Ain, short* Aout, short* Bs0, short* Bs1,
    const short* myAst, short* Ast0, short* Ast1,
    const char* gA0, const char* gA1,
    const char* gB0, const char* gB1, const char* gB2,
    const char* gB3, const char* gB4, const float* __restrict__ biasp)
{
    constexpr int MT  = (MA + 15) / 16;     // 4,2,1,1,1,1
    constexpr int TPW = MT * 5;             // tiles per 4-wave group
    const int lrow = lane & 15;
    const int hi   = lane >> 4;

    float4v acc[TPW];
#pragma unroll
    for (int t = 0; t < TPW; ++t) acc[t] = (float4v)0.f;

    auto stage = [&](int buf, int kc) {
        if (w < 4) {                        // waves 0-3: B plane (shared)
            char* base = (char*)(buf ? Bs1 : Bs0);
            GLL16(gB0 + kc * 64, base + (w * 5 + 0) * 1024);
            GLL16(gB1 + kc * 64, base + (w * 5 + 1) * 1024);
            GLL16(gB2 + kc * 64, base + (w * 5 + 2) * 1024);
            GLL16(gB3 + kc * 64, base + (w * 5 + 3) * 1024);
            GLL16(gB4 + kc * 64, base + (w * 5 + 4) * 1024);
        } else if (STREAM) {                // waves 4-7: both A-streams
            const int off = (kc >= 10 ? 640 : 0) + (kc % 10) * 64;
            GLL16(gA0 + off, (char*)Ast0 + buf * 4096 + (w - 4) * 1024);
            GLL16(gA1 + off, (char*)Ast1 + buf * 4096 + (w - 4) * 1024);
        }
    };

    stage(0, 0);
    for (int kc = 0; kc < 20; ++kc) {
        const int cur = kc & 1;
        if (kc + 1 < 20) {
            stage(cur ^ 1, kc + 1);
            // wait only chunk kc's loads (newest stay in flight)
            if (w < 4)       asm volatile("s_waitcnt vmcnt(5)" ::: "memory");
            else if (STREAM) asm volatile("s_waitcnt vmcnt(2)" ::: "memory");
        } else {
            asm volatile("s_waitcnt vmcnt(0)" ::: "memory");
        }
        __builtin_amdgcn_s_barrier();
        __builtin_amdgcn_sched_barrier(0);

        const short* Bsc = cur ? Bs1 : Bs0;
#pragma unroll
        for (int t = 0; t < TPW; ++t) {
            const int g  = wl + t * 4;
            const int mt = g / 20, nt = g % 20;
            int row = mt * 16 + lrow;
            if (MA < 16) row = (lrow < MA) ? lrow : 0;   // clamp garbage rows
            const int sa = hi ^ ((row >> 1) & 3);
            const short* pa = STREAM
                ? (myAst + cur * 2048 + row * 32 + sa * 8)
                : (Ain + kc * (MA * 32) + row * 32 + sa * 8);
            const int n  = nt * 16 + lrow;
            const int sb = hi ^ ((n >> 1) & 3);
            const short8 a = *(const short8*)pa;
            const short8 b = *(const short8*)(Bsc + n * 32 + sb * 8);
            acc[t] = __builtin_amdgcn_mfma_f32_16x16x32_bf16(
                a, b, acc[t], 0, 0, 0);
        }
        __builtin_amdgcn_s_barrier();   // reads of buf[cur] done; next iter's
                                        // stage may overwrite it
    }

#pragma unroll
    for (int t = 0; t < TPW; ++t) {
        const int g  = wl + t * 4;
        const int mt = g / 20, nt = g % 20;
        const int c  = nt * 16 + lrow;
        const float bv = biasp[c];
#pragma unroll
        for (int r4 = 0; r4 < 4; ++r4) {
            const int mb = mt * 16 + hi * 4 + r4;
            if (mb < MA) {
                const short v = f2bs(acc[t][r4] + bv);
                if (TOROOTS) {
                    Aout[mb * 320 + c] = v;
                } else {
                    constexpr int MN = MA / 2;           // next level A-rows
                    const int p  = (mb & 1) * 10 + (c >> 5);
                    const int m2 = mb >> 1;
                    const int q  = (c >> 3) & 3;
                    Aout[p * (MN * 32) + m2 * 32 +
                         (q ^ ((m2 >> 1) & 3)) * 8 + (c & 7)] = v;
                }
            }
        }
    }
    __syncthreads();   // next-A visible to all waves before next level
}

__global__ __launch_bounds__(512, 1) void subtree(
    const short* __restrict__ L2in, const short* __restrict__ Wp,
    const float* __restrict__ biasp, const float* __restrict__ W_cls,
    const float* __restrict__ b_cls, float* __restrict__ outp)
{
    __shared__ __align__(16) short Bs[2][320 * 32];     // 2 x 20 KB
    __shared__ __align__(16) short AXs[2][20 * 32 * 32];// 2 x 40 KB
    __shared__ __align__(16) short AYs[2][10240];       // 2 x 20 KB = 160 KiB

    const int tid  = threadIdx.x;
    const int lane = tid & 63;
    const int w    = tid >> 6;            // 0..7
    const int wl   = w & 3;               // wave within group
    const int grp  = w >> 2;              // batch group 0/1
    const int s_q   = lane & 3;
    const int r_off = lane >> 2;

    const char* gB[5];
#pragma unroll
    for (int j = 0; j < 5; ++j) {
        const int r = (wl * 5 + j) * 16 + r_off;      // 0..319 (used by w<4)
        const int q = s_q ^ ((r >> 1) & 3);
        gB[j] = (const char*)Wp + r * 1280L + q * 16;
    }
    // L3 A-stream bases (used by waves 4-7, one GLL per batch)
    const int wa = (w >= 4) ? (w - 4) : 0;
    const int rS = wa * 16 + r_off;                   // 0..63
    const int qS = s_q ^ ((rS >> 1) & 3);
    const long base0 = (long)(2 * blockIdx.x) * 128;
    const char* gA0 = (const char*)L2in + (base0 + 2 * rS) * 640 + qS * 16;
    const char* gA1 = (const char*)L2in + (base0 + 128 + 2 * rS) * 640 + qS * 16;

    short* AXm = AXs[grp];
    short* AYm = AYs[grp];

    // L3: 64 rows (A streamed into AYs[grp] 2-plane ring) -> L4A in AXm
    tree_level<64, true,  false>(w, wl, lane, nullptr, AXm, Bs[0], Bs[1],
                                 AYs[grp], AYs[0], AYs[1], gA0, gA1,
                                 gB[0], gB[1], gB[2], gB[3], gB[4], biasp);
    // L4: 32 -> AYm (overwrites the now-dead A-stage ring)
    tree_level<32, false, false>(w, wl, lane, AXm, AYm, Bs[0], Bs[1],
                                 nullptr, nullptr, nullptr, nullptr, nullptr,
                                 gB[0], gB[1], gB[2], gB[3], gB[4], biasp);
    // L5: 16 -> AXm
    tree_level<16, false, false>(w, wl, lane, AYm, AXm, Bs[0], Bs[1],
                                 nullptr, nullptr, nullptr, nullptr, nullptr,
                                 gB[0], gB[1], gB[2], gB[3], gB[4], biasp);
    // L6: 8 -> AYm
    tree_level<8,  false, false>(w, wl, lane, AXm, AYm, Bs[0], Bs[1],
                                 nullptr, nullptr, nullptr, nullptr, nullptr,
                                 gB[0], gB[1], gB[2], gB[3], gB[4], biasp);
    // L7: 4 -> AXm
    tree_level<4,  false, false>(w, wl, lane, AYm, AXm, Bs[0], Bs[1],
                                 nullptr, nullptr, nullptr, nullptr, nullptr,
                                 gB[0], gB[1], gB[2], gB[3], gB[4], biasp);
    // L8: 2 roots (plain 2x320) -> AYm
    tree_level<2,  false, true >(w, wl, lane, AXm, AYm, Bs[0], Bs[1],
                                 nullptr, nullptr, nullptr, nullptr, nullptr,
                                 gB[0], gB[1], gB[2], gB[3], gB[4], biasp);

    // classifier: wave 0 -> batch 2*blk, wave 4 -> batch 2*blk+1
    if (wl == 0) {
        const short* rowp = AYs[grp];
        float a0 = 0.f, a1 = 0.f, a2 = 0.f;
#pragma unroll
        for (int i = 0; i < 10; ++i) {
            const int k = lane + 64 * i;
            if (k < 600) {
                const int col = (k < 300) ? k : (320 + k - 300);
                const float f = 1.f / (1.f + __expf(-bs2f(rowp[col])));
                a0 += f * W_cls[k];
                a1 += f * W_cls[600 + k];
                a2 += f * W_cls[1200 + k];
            }
        }
#pragma unroll
        for (int off = 32; off > 0; off >>= 1) {
            a0 += __shfl_down(a0, off);
            a1 += __shfl_down(a1, off);
            a2 += __shfl_down(a2, off);
        }
        if (lane == 0) {
            const int b = blockIdx.x * 2 + grp;
            const float l0 = a0 + b_cls[0];
            const float l1 = a1 + b_cls[1];
            const float l2 = a2 + b_cls[2];
            const float m  = fmaxf(l0, fmaxf(l1, l2));
            const float s  = __expf(l0 - m) + __expf(l1 - m) + __expf(l2 - m);
            const float ls = m + __logf(s);
            outp[b * 3 + 0] = l0 - ls;
            outp[b * 3 + 1] = l1 - ls;
            outp[b * 3 + 2] = l2 - ls;
        }
    }
}

extern "C" void kernel_launch(void* const* d_in, const int* in_sizes, int n_in,
                              void* d_out, int out_size, void* d_ws, size_t ws_size,
                              hipStream_t stream)
{
    const int*   wid    = (const int*)d_in[0];     // (512,2,256) int32
    const float* emb    = (const float*)d_in[1];   // (50000,300) f32
    const float* W_leaf = (const float*)d_in[2];   // (300,300)
    const float* W_h    = (const float*)d_in[3];   // (300,600)
    const float* b_h    = (const float*)d_in[4];   // (300,)
    const float* W_cls  = (const float*)d_in[5];   // (3,600)
    const float* b_cls  = (const float*)d_in[6];   // (3,)
    float* outp = (float*)d_out;                   // (512,3) f32

    (void)in_sizes; (void)n_in; (void)out_size; (void)ws_size;

    // ws layout (peak 158,557,440 B):
    //   bufA   @ 0           : 131072*320*2 =  83,886,080  (L1 out)
    //   bufB   @  83,886,080 :  65536*320*2 =  41,943,040  (L2 out)
    //   emb_bf @  83,886,080 : 50176*320*2  =  32,112,640  (ALIASES bufB: dead
    //            after Hv GEMM; bufB first written by L2, which runs later)
    //   Hv     @ 125,829,120 : 50176*320*2  =  32,112,640
    //   Bleaf  @ 157,941,760 : 320*320*2    =     204,800
    //   Bh     @ 158,146,560 : 320*640*2    =     409,600
    //   biasp  @ 158,556,160 : 320*4        =       1,280
    char* ws = (char*)d_ws;
    short* bufA   = (short*)(ws);
    short* bufB   = (short*)(ws + 83886080);
    short* emb_bf = (short*)(ws + 83886080);
    short* Hv     = (short*)(ws + 125829120);
    short* Bleaf  = (short*)(ws + 157941760);
    short* Bh     = (short*)(ws + 158146560);
    float* biasp  = (float*)(ws + 158556160);

    // fused preprocessing: 4,321,600 work items
    conv_all<<<(4321600 + 255) / 256, 256, 0, stream>>>(
        emb, W_h, W_leaf, b_h, emb_bf, Bh, Bleaf, biasp);

    // Vocab-level leaf transform: Hv = emb_bf @ Bleaf^T, M=50176.
    mfma_gemm<320, 0, false><<<50176 / 128, 256, 0, stream>>>(
        emb_bf, nullptr, nullptr, Bleaf, biasp, Hv);

    // L1: node m = W_h @ concat(Hv[wid[2m]], Hv[wid[2m+1]]) + b_h -> bufA.
    mfma_gemm<640, 2, true><<<131072 / 128, 256, 0, stream>>>(
        nullptr, wid, Hv, Bh, biasp, bufA);

    // L2: throughput GEMM, 512 blocks (2/CU): bufA -> bufB (65536 rows).
    mfma_gemm<640, 0, true><<<65536 / 128, 256, 0, stream>>>(
        bufA, nullptr, nullptr, Bh, biasp, bufB);

    // L3..L8 + classifier: 256 blocks (1/CU), 2 batches/block, B dbuf'd.
    subtree<<<256, 512, 0, stream>>>(bufB, Bh, biasp, W_cls, b_cls, outp);
}

// Round 17
// 292.264 us; speedup vs baseline: 1.9287x; 1.0041x over previous
//
#include <hip/hip_runtime.h>
#include <hip/hip_bf16.h>

typedef __hip_bfloat16 bf16;
typedef __attribute__((ext_vector_type(8))) short short8;   // 8 bf16 = 4 VGPRs
typedef __attribute__((ext_vector_type(4))) float float4v;  // MFMA C/D
typedef __attribute__((ext_vector_type(4))) short short4v;

__device__ __forceinline__ short f2bs(float x) {
    bf16 b = __float2bfloat16(x);
    return *reinterpret_cast<short*>(&b);
}
__device__ __forceinline__ float bs2f(short s) {
    bf16 b = *reinterpret_cast<bf16*>(&s);
    return __bfloat162float(b);
}

#define GLL16(g, l) __builtin_amdgcn_global_load_lds(                      \
    (const __attribute__((address_space(1))) void*)(g),                    \
    (__attribute__((address_space(3))) void*)(l), 16, 0, 0)

// ---------------- fused preprocessing: one kernel, region-split -----------
__global__ __launch_bounds__(256) void conv_all(
    const float* __restrict__ emb, const float* __restrict__ W_h,
    const float* __restrict__ W_leaf, const float* __restrict__ b_h,
    short* __restrict__ emb_bf, short* __restrict__ Bh,
    short* __restrict__ Bleaf, float* __restrict__ biasp)
{
    const int idx = blockIdx.x * 256 + threadIdx.x;
    if (idx < 4014080) {                                  // emb region
        const int row = idx / 80;
        const int k4  = (idx - row * 80) * 4;
        short4v v = (short4v)0;
        if (row < 50000 && k4 < 300) {
            const float4v f = *reinterpret_cast<const float4v*>(
                emb + (long)row * 300 + k4);
#pragma unroll
            for (int j = 0; j < 4; ++j) v[j] = f2bs(f[j]);
        }
        *(short4v*)&emb_bf[(long)row * 320 + k4] = v;
        return;
    }
    const int j = idx - 4014080;
    if (j < 204800) {                                     // Bh 320x640
        const int row = j / 640, k = j - row * 640;
        float v = 0.f;
        if (row < 300) {
            if (k < 300)                  v = W_h[row * 600 + k];
            else if (k >= 320 && k < 620) v = W_h[row * 600 + k - 20];
        }
        Bh[j] = f2bs(v);
    } else if (j < 307200) {                              // Bleaf 320x320
        const int i = j - 204800;
        const int row = i / 320, k = i - row * 320;
        Bleaf[i] = (row < 300 && k < 300) ? f2bs(W_leaf[row * 300 + k])
                                          : (short)0;
    } else if (j < 307520) {                              // biasp 320
        const int i = j - 307200;
        biasp[i] = (i < 300) ? b_h[i] : 0.f;
    }
}

// ---------------- MFMA GEMM (BK=32, 2-buf, 1-deep counted vmcnt) ----------
// Used for Hv (KE=320), L1 (gather, KE=640), L2 (KE=640). 2 blocks/CU.
template <int KE, int GMODE, bool BIAS>
__global__ __launch_bounds__(256, 2) void mfma_gemm(
    const short* __restrict__ Xsrc, const int* __restrict__ wid,
    const short* __restrict__ emb, const short* __restrict__ Wp,
    const float* __restrict__ biasp, short* __restrict__ out)
{
    static_assert(GMODE != 2 || KE == 640, "pair-gather requires KE=640");
    __shared__ __align__(16) short As[2][128 * 32];   // 2 x 8 KB
    __shared__ __align__(16) short Bs[2][320 * 32];   // 2 x 20 KB

    const int tid  = threadIdx.x;
    const int lane = tid & 63;
    const int w    = tid >> 6;
    const int wm   = w >> 1, wn = w & 1;
    const long m0  = (long)blockIdx.x * 128;

    const int s_q   = lane & 3;
    const int r_off = lane >> 2;

    const char* gL[2];
    const char* gR[2];
#pragma unroll
    for (int j = 0; j < 2; ++j) {
        const int r = (w * 2 + j) * 16 + r_off;            // 0..127
        const int q = s_q ^ ((r >> 1) & 3);
        if (GMODE == 2) {
            const long node = m0 + r;
            gL[j] = (const char*)emb + (long)wid[2 * node]     * 640 + q * 16;
            gR[j] = (const char*)emb + (long)wid[2 * node + 1] * 640 + q * 16;
        } else {
            gL[j] = (const char*)Xsrc + (m0 + r) * (long)(KE * 2) + q * 16;
            gR[j] = gL[j];
        }
    }
    const char* gB[5];
#pragma unroll
    for (int j = 0; j < 5; ++j) {
        const int r = (w * 5 + j) * 16 + r_off;            // 0..319
        const int q = s_q ^ ((r >> 1) & 3);
        gB[j] = (const char*)Wp + r * (long)(KE * 2) + q * 16;
    }

    int oA[4];
#pragma unroll
    for (int t = 0; t < 4; ++t) {
        const int row = wm * 64 + t * 16 + (lane & 15);
        const int s   = (lane >> 4) ^ ((row >> 1) & 3);
        oA[t] = row * 32 + s * 8;
    }
    int oB[10];
#pragma unroll
    for (int u = 0; u < 10; ++u) {
        const int n = wn * 160 + u * 16 + (lane & 15);
        const int s = (lane >> 4) ^ ((n >> 1) & 3);
        oB[u] = n * 32 + s * 8;
    }

    auto stage = [&](int buf, int kc) {
        char* baseA = (char*)&As[buf][0];
        char* baseB = (char*)&Bs[buf][0];
        if (GMODE == 2) {
            const bool lft = (kc < 10);
            const int off = (lft ? kc : kc - 10) * 64;
            GLL16((lft ? gL[0] : gR[0]) + off, baseA + (w * 2 + 0) * 1024);
            GLL16((lft ? gL[1] : gR[1]) + off, baseA + (w * 2 + 1) * 1024);
        } else {
            const int off = kc * 64;
            GLL16(gL[0] + off, baseA + (w * 2 + 0) * 1024);
            GLL16(gL[1] + off, baseA + (w * 2 + 1) * 1024);
        }
        const int offb = kc * 64;
#pragma unroll
        for (int j = 0; j < 5; ++j)
            GLL16(gB[j] + offb, baseB + (w * 5 + j) * 1024);
    };

    float4v acc[4][10];
#pragma unroll
    for (int t = 0; t < 4; ++t)
#pragma unroll
        for (int u = 0; u < 10; ++u) acc[t][u] = (float4v)0.f;

    const int NCH = KE / 32;
    stage(0, 0);
    for (int kc = 0; kc < NCH; ++kc) {
        const int cur = kc & 1;
        if (kc + 1 < NCH) {
            stage(cur ^ 1, kc + 1);
            asm volatile("s_waitcnt vmcnt(7)" ::: "memory");
        } else {
            asm volatile("s_waitcnt vmcnt(0)" ::: "memory");
        }
        __builtin_amdgcn_s_barrier();
        __builtin_amdgcn_sched_barrier(0);

        const short* bA = &As[cur][0];
        const short* bB = &Bs[cur][0];
        short8 a[4], b[10];
#pragma unroll
        for (int t = 0; t < 4; ++t) a[t] = *(const short8*)(bA + oA[t]);
#pragma unroll
        for (int u = 0; u < 10; ++u) b[u] = *(const short8*)(bB + oB[u]);
#pragma unroll
        for (int u = 0; u < 10; ++u)
#pragma unroll
            for (int t = 0; t < 4; ++t)
                acc[t][u] = __builtin_amdgcn_mfma_f32_16x16x32_bf16(
                    a[t], b[u], acc[t][u], 0, 0, 0);
        __builtin_amdgcn_s_barrier();
    }

#pragma unroll
    for (int u = 0; u < 10; ++u) {
        const int c = wn * 160 + u * 16 + (lane & 15);
        const float bv = BIAS ? biasp[c] : 0.f;
#pragma unroll
        for (int t = 0; t < 4; ++t) {
            const long mb = m0 + wm * 64 + t * 16 + (lane >> 4) * 4;
#pragma unroll
            for (int r4 = 0; r4 < 4; ++r4)
                out[(mb + r4) * 320 + c] = f2bs(acc[t][u][r4] + bv);
        }
    }
}

// ---------------- per-CU dual-batch subtree: L3..L8 + classifier ----------
// Round-16: 77.7 us — LDS-read-BW bound: old inner loop issued a fresh A-read
// + B-read PER MFMA (L3: 320 KB ds_read per plane-iter per CU ~ 2500 cy,
// 13x the MFMA time). Fix: register-cache fragments. Per wave the (mt,nt)
// tile set is exactly {mt in [0,MT)} x {nt = wl+4j, j in [0,5)}: load a[MT]
// + b[5] once per plane-iter, then run MT*5 MFMAs (the mfma_gemm pattern).
// acc index bijection t = mt*5+j (g = wl+20mt+4j) -> identical MFMA sequence
// and accumulation order per acc element -> bit-identical results.
// LDS traffic/iter/wave: L3 40->9 KB, L4 20->7, L5-L8 10->6.
template<int MA, bool STREAM, bool TOROOTS>
__device__ __forceinline__ void tree_level(
    const int w, const int wl, const int lane,
    const short* Ain, short* Aout, short* Bs0, short* Bs1,
    const short* myAst, short* Ast0, short* Ast1,
    const char* gA0, const char* gA1,
    const char* gB0, const char* gB1, const char* gB2,
    const char* gB3, const char* gB4, const float* __restrict__ biasp)
{
    constexpr int MT  = (MA + 15) / 16;     // 4,2,1,1,1,1
    const int lrow = lane & 15;
    const int hi   = lane >> 4;

    float4v acc[MT][5];
#pragma unroll
    for (int mt = 0; mt < MT; ++mt)
#pragma unroll
        for (int j = 0; j < 5; ++j) acc[mt][j] = (float4v)0.f;

    // per-wave fragment LDS offsets (buffer-invariant parts)
    int oA[MT];
#pragma unroll
    for (int mt = 0; mt < MT; ++mt) {
        int row = mt * 16 + lrow;
        if (MA < 16) row = (lrow < MA) ? lrow : 0;       // clamp garbage rows
        const int sa = hi ^ ((row >> 1) & 3);
        oA[mt] = row * 32 + sa * 8;
    }
    int oB[5];
#pragma unroll
    for (int j = 0; j < 5; ++j) {
        const int n = (wl + 4 * j) * 16 + lrow;
        const int sb = hi ^ ((n >> 1) & 3);
        oB[j] = n * 32 + sb * 8;
    }

    auto stage = [&](int buf, int kc) {
        if (w < 4) {                        // waves 0-3: B plane (shared)
            char* base = (char*)(buf ? Bs1 : Bs0);
            GLL16(gB0 + kc * 64, base + (w * 5 + 0) * 1024);
            GLL16(gB1 + kc * 64, base + (w * 5 + 1) * 1024);
            GLL16(gB2 + kc * 64, base + (w * 5 + 2) * 1024);
            GLL16(gB3 + kc * 64, base + (w * 5 + 3) * 1024);
            GLL16(gB4 + kc * 64, base + (w * 5 + 4) * 1024);
        } else if (STREAM) {                // waves 4-7: both A-streams
            const int off = (kc >= 10 ? 640 : 0) + (kc % 10) * 64;
            GLL16(gA0 + off, (char*)Ast0 + buf * 4096 + (w - 4) * 1024);
            GLL16(gA1 + off, (char*)Ast1 + buf * 4096 + (w - 4) * 1024);
        }
    };

    stage(0, 0);
    for (int kc = 0; kc < 20; ++kc) {
        const int cur = kc & 1;
        if (kc + 1 < 20) {
            stage(cur ^ 1, kc + 1);
            // wait only chunk kc's loads (newest stay in flight)
            if (w < 4)       asm volatile("s_waitcnt vmcnt(5)" ::: "memory");
            else if (STREAM) asm volatile("s_waitcnt vmcnt(2)" ::: "memory");
        } else {
            asm volatile("s_waitcnt vmcnt(0)" ::: "memory");
        }
        __builtin_amdgcn_s_barrier();
        __builtin_amdgcn_sched_barrier(0);

        const short* Bsc = cur ? Bs1 : Bs0;
        const short* Abase = STREAM ? (myAst + cur * 2048)
                                    : (Ain + kc * (MA * 32));
        short8 a[MT], b[5];
#pragma unroll
        for (int mt = 0; mt < MT; ++mt)
            a[mt] = *(const short8*)(Abase + oA[mt]);
#pragma unroll
        for (int j = 0; j < 5; ++j)
            b[j] = *(const short8*)(Bsc + oB[j]);
#pragma unroll
        for (int mt = 0; mt < MT; ++mt)
#pragma unroll
            for (int j = 0; j < 5; ++j)
                acc[mt][j] = __builtin_amdgcn_mfma_f32_16x16x32_bf16(
                    a[mt], b[j], acc[mt][j], 0, 0, 0);
        __builtin_amdgcn_s_barrier();   // reads of buf[cur] done; next iter's
                                        // stage may overwrite it
    }

#pragma unroll
    for (int mt = 0; mt < MT; ++mt)
#pragma unroll
    for (int j = 0; j < 5; ++j) {
        const int c  = (wl + 4 * j) * 16 + lrow;
        const float bv = biasp[c];
#pragma unroll
        for (int r4 = 0; r4 < 4; ++r4) {
            const int mb = mt * 16 + hi * 4 + r4;
            if (mb < MA) {
                const short v = f2bs(acc[mt][j][r4] + bv);
                if (TOROOTS) {
                    Aout[mb * 320 + c] = v;
                } else {
                    constexpr int MN = MA / 2;           // next level A-rows
                    const int p  = (mb & 1) * 10 + (c >> 5);
                    const int m2 = mb >> 1;
                    const int q  = (c >> 3) & 3;
                    Aout[p * (MN * 32) + m2 * 32 +
                         (q ^ ((m2 >> 1) & 3)) * 8 + (c & 7)] = v;
                }
            }
        }
    }
    __syncthreads();   // next-A visible to all waves before next level
}

__global__ __launch_bounds__(512, 1) void subtree(
    const short* __restrict__ L2in, const short* __restrict__ Wp,
    const float* __restrict__ biasp, const float* __restrict__ W_cls,
    const float* __restrict__ b_cls, float* __restrict__ outp)
{
    __shared__ __align__(16) short Bs[2][320 * 32];     // 2 x 20 KB
    __shared__ __align__(16) short AXs[2][20 * 32 * 32];// 2 x 40 KB
    __shared__ __align__(16) short AYs[2][10240];       // 2 x 20 KB = 160 KiB

    const int tid  = threadIdx.x;
    const int lane = tid & 63;
    const int w    = tid >> 6;            // 0..7
    const int wl   = w & 3;               // wave within group
    const int grp  = w >> 2;              // batch group 0/1
    const int s_q   = lane & 3;
    const int r_off = lane >> 2;

    const char* gB[5];
#pragma unroll
    for (int j = 0; j < 5; ++j) {
        const int r = (wl * 5 + j) * 16 + r_off;      // 0..319 (used by w<4)
        const int q = s_q ^ ((r >> 1) & 3);
        gB[j] = (const char*)Wp + r * 1280L + q * 16;
    }
    // L3 A-stream bases (used by waves 4-7, one GLL per batch)
    const int wa = (w >= 4) ? (w - 4) : 0;
    const int rS = wa * 16 + r_off;                   // 0..63
    const int qS = s_q ^ ((rS >> 1) & 3);
    const long base0 = (long)(2 * blockIdx.x) * 128;
    const char* gA0 = (const char*)L2in + (base0 + 2 * rS) * 640 + qS * 16;
    const char* gA1 = (const char*)L2in + (base0 + 128 + 2 * rS) * 640 + qS * 16;

    short* AXm = AXs[grp];
    short* AYm = AYs[grp];

    // L3: 64 rows (A streamed into AYs[grp] 2-plane ring) -> L4A in AXm
    tree_level<64, true,  false>(w, wl, lane, nullptr, AXm, Bs[0], Bs[1],
                                 AYs[grp], AYs[0], AYs[1], gA0, gA1,
                                 gB[0], gB[1], gB[2], gB[3], gB[4], biasp);
    // L4: 32 -> AYm (overwrites the now-dead A-stage ring)
    tree_level<32, false, false>(w, wl, lane, AXm, AYm, Bs[0], Bs[1],
                                 nullptr, nullptr, nullptr, nullptr, nullptr,
                                 gB[0], gB[1], gB[2], gB[3], gB[4], biasp);
    // L5: 16 -> AXm
    tree_level<16, false, false>(w, wl, lane, AYm, AXm, Bs[0], Bs[1],
                                 nullptr, nullptr, nullptr, nullptr, nullptr,
                                 gB[0], gB[1], gB[2], gB[3], gB[4], biasp);
    // L6: 8 -> AYm
    tree_level<8,  false, false>(w, wl, lane, AXm, AYm, Bs[0], Bs[1],
                                 nullptr, nullptr, nullptr, nullptr, nullptr,
                                 gB[0], gB[1], gB[2], gB[3], gB[4], biasp);
    // L7: 4 -> AXm
    tree_level<4,  false, false>(w, wl, lane, AYm, AXm, Bs[0], Bs[1],
                                 nullptr, nullptr, nullptr, nullptr, nullptr,
                                 gB[0], gB[1], gB[2], gB[3], gB[4], biasp);
    // L8: 2 roots (plain 2x320) -> AYm
    tree_level<2,  false, true >(w, wl, lane, AXm, AYm, Bs[0], Bs[1],
                                 nullptr, nullptr, nullptr, nullptr, nullptr,
                                 gB[0], gB[1], gB[2], gB[3], gB[4], biasp);

    // classifier: wave 0 -> batch 2*blk, wave 4 -> batch 2*blk+1
    if (wl == 0) {
        const short* rowp = AYs[grp];
        float a0 = 0.f, a1 = 0.f, a2 = 0.f;
#pragma unroll
        for (int i = 0; i < 10; ++i) {
            const int k = lane + 64 * i;
            if (k < 600) {
                const int col = (k < 300) ? k : (320 + k - 300);
                const float f = 1.f / (1.f + __expf(-bs2f(rowp[col])));
                a0 += f * W_cls[k];
                a1 += f * W_cls[600 + k];
                a2 += f * W_cls[1200 + k];
            }
        }
#pragma unroll
        for (int off = 32; off > 0; off >>= 1) {
            a0 += __shfl_down(a0, off);
            a1 += __shfl_down(a1, off);
            a2 += __shfl_down(a2, off);
        }
        if (lane == 0) {
            const int b = blockIdx.x * 2 + grp;
            const float l0 = a0 + b_cls[0];
            const float l1 = a1 + b_cls[1];
            const float l2 = a2 + b_cls[2];
            const float m  = fmaxf(l0, fmaxf(l1, l2));
            const float s  = __expf(l0 - m) + __expf(l1 - m) + __expf(l2 - m);
            const float ls = m + __logf(s);
            outp[b * 3 + 0] = l0 - ls;
            outp[b * 3 + 1] = l1 - ls;
            outp[b * 3 + 2] = l2 - ls;
        }
    }
}

extern "C" void kernel_launch(void* const* d_in, const int* in_sizes, int n_in,
                              void* d_out, int out_size, void* d_ws, size_t ws_size,
                              hipStream_t stream)
{
    const int*   wid    = (const int*)d_in[0];     // (512,2,256) int32
    const float* emb    = (const float*)d_in[1];   // (50000,300) f32
    const float* W_leaf = (const float*)d_in[2];   // (300,300)
    const float* W_h    = (const float*)d_in[3];   // (300,600)
    const float* b_h    = (const float*)d_in[4];   // (300,)
    const float* W_cls  = (const float*)d_in[5];   // (3,600)
    const float* b_cls  = (const float*)d_in[6];   // (3,)
    float* outp = (float*)d_out;                   // (512,3) f32

    (void)in_sizes; (void)n_in; (void)out_size; (void)ws_size;

    // ws layout (peak 158,557,440 B):
    //   bufA   @ 0           : 131072*320*2 =  83,886,080  (L1 out)
    //   bufB   @  83,886,080 :  65536*320*2 =  41,943,040  (L2 out)
    //   emb_bf @  83,886,080 : 50176*320*2  =  32,112,640  (ALIASES bufB: dead
    //            after Hv GEMM; bufB first written by L2, which runs later)
    //   Hv     @ 125,829,120 : 50176*320*2  =  32,112,640
    //   Bleaf  @ 157,941,760 : 320*320*2    =     204,800
    //   Bh     @ 158,146,560 : 320*640*2    =     409,600
    //   biasp  @ 158,556,160 : 320*4        =       1,280
    char* ws = (char*)d_ws;
    short* bufA   = (short*)(ws);
    short* bufB   = (short*)(ws + 83886080);
    short* emb_bf = (short*)(ws + 83886080);
    short* Hv     = (short*)(ws + 125829120);
    short* Bleaf  = (short*)(ws + 157941760);
    short* Bh     = (short*)(ws + 158146560);
    float* biasp  = (float*)(ws + 158556160);

    // fused preprocessing: 4,321,600 work items
    conv_all<<<(4321600 + 255) / 256, 256, 0, stream>>>(
        emb, W_h, W_leaf, b_h, emb_bf, Bh, Bleaf, biasp);

    // Vocab-level leaf transform: Hv = emb_bf @ Bleaf^T, M=50176.
    mfma_gemm<320, 0, false><<<50176 / 128, 256, 0, stream>>>(
        emb_bf, nullptr, nullptr, Bleaf, biasp, Hv);

    // L1: node m = W_h @ concat(Hv[wid[2m]], Hv[wid[2m+1]]) + b_h -> bufA.
    mfma_gemm<640, 2, true><<<131072 / 128, 256, 0, stream>>>(
        nullptr, wid, Hv, Bh, biasp, bufA);

    // L2: throughput GEMM, 512 blocks (2/CU): bufA -> bufB (65536 rows).
    mfma_gemm<640, 0, true><<<65536 / 128, 256, 0, stream>>>(
        bufA, nullptr, nullptr, Bh, biasp, bufB);

    // L3..L8 + classifier: 256 blocks (1/CU), 2 batches/block, B dbuf'd,
    // register-cached fragments (a[MT] + b[5] -> MT*5 MFMAs per iter).
    subtree<<<256, 512, 0, stream>>>(bufB, Bh, biasp, W_cls, b_cls, outp);
}